// Round 10
// baseline (286.969 us; speedup 1.0000x reference)
//
#include <hip/hip_runtime.h>
#include <math.h>

__device__ __forceinline__ float sigf(float x) { return 1.f / (1.f + expf(-x)); }

using half8v = __attribute__((ext_vector_type(8))) _Float16;
using f32x4  = __attribute__((ext_vector_type(4))) float;
using f32x16 = __attribute__((ext_vector_type(16))) float;

__device__ __forceinline__ unsigned short f2h(float x) {
    union { _Float16 h; unsigned short u; } c; c.h = (_Float16)x; return c.u;
}

// ---------------------------------------------------------------------------
// Templated row-matmul+ReLU: compile-time K, LDS-staged W and rows, 8-row
// register blocking per wave. unroll-2 + launch_bounds(256,4): VGPR bounded
// (round-8 full-unroll spilled: VGPR=256, 133MB scratch writes).
// ---------------------------------------------------------------------------
template<int K, int MODE>
__global__ __launch_bounds__(256, 4)
void rowmat_relu_t(const float* __restrict__ in, const float* __restrict__ W,
                   const float* __restrict__ b, float* __restrict__ out32,
                   _Float16* __restrict__ out16, int R)
{
    __shared__ float Wl[K * 64];
    __shared__ float rowsS[32 * K];

    const int tid  = threadIdx.x;
    const int row0 = blockIdx.x * 32;

    for (int i = tid; i < K * 64; i += 256)
        Wl[i] = W[i];
    const int lim = (R - row0 >= 32 ? 32 : (R - row0)) * K;
    for (int i = tid; i < 32 * K; i += 256)
        rowsS[i] = (i < lim) ? in[(size_t)row0 * K + i] : 0.f;
    __syncthreads();

    const int wave = tid >> 6, lane = tid & 63;
    const float bv = b[lane];

    float acc[8];
    #pragma unroll
    for (int rr = 0; rr < 8; ++rr) acc[rr] = bv;

    #pragma unroll 2
    for (int k = 0; k < K; ++k) {
        const float wv = Wl[k * 64 + lane];
        #pragma unroll
        for (int rr = 0; rr < 8; ++rr)
            acc[rr] = fmaf(rowsS[(wave * 8 + rr) * K + k], wv, acc[rr]);
    }

    #pragma unroll
    for (int rr = 0; rr < 8; ++rr) {
        const int row = row0 + wave * 8 + rr;
        if (row < R) {
            const float v = fmaxf(acc[rr], 0.f);
            if (MODE == 0) out32[(size_t)row * 64 + lane] = v;
            out16[(size_t)row * 64 + lane] = (_Float16)v;
        }
    }
}

// ---------------------------------------------------------------------------
// One-time edge-net weight prep (f16, swizzled, chunk-major) — validated.
// ---------------------------------------------------------------------------
__global__ __launch_bounds__(256)
void prep_w_kernel(const float* __restrict__ eW2, const float* __restrict__ eb2,
                   unsigned short* __restrict__ w_staged)
{
    int slot = blockIdx.x * 256 + threadIdx.x;     // 65*512 slots
    if (slot >= 65 * 512) return;
    int kc  = slot >> 9;
    int s   = slot & 511;
    int o   = s >> 3, seg = s & 7;
    unsigned int packed[4];
    #pragma unroll
    for (int p = 0; p < 4; ++p) {
        int j0 = kc * 64 + seg * 8 + p * 2;
        float v0 = (j0     < 4096) ? eW2[(size_t)j0 * 64 + o]       : eb2[(size_t)(j0 - 4096) * 64 + o];
        float v1 = (j0 + 1 < 4096) ? eW2[(size_t)(j0 + 1) * 64 + o] : eb2[(size_t)(j0 + 1 - 4096) * 64 + o];
        packed[p] = (unsigned int)f2h(v0) | ((unsigned int)f2h(v1) << 16);
    }
    int dstb = ((o * 128) + seg * 16) ^ ((o & 7) << 4);
    uint4 st = {packed[0], packed[1], packed[2], packed[3]};
    *(uint4*)((char*)w_staged + (size_t)kc * 8192 + dstb) = st;
}

// ---------------------------------------------------------------------------
// One-time GRU weight prep: WiT/WhT[n][k] = (f16) W[k*192+n].
// ---------------------------------------------------------------------------
__global__ __launch_bounds__(256)
void prep_gruw_kernel(const float* __restrict__ Wi, const float* __restrict__ Wh,
                      _Float16* __restrict__ WiT, _Float16* __restrict__ WhT)
{
    int idx = blockIdx.x * 256 + threadIdx.x;
    if (idx >= 2 * 12288) return;
    const float* W = (idx < 12288) ? Wi : Wh;
    _Float16*    O = (idx < 12288) ? WiT : WhT;
    int r = idx & 12287;
    int n = r >> 6, k = r & 63;
    O[n * 64 + k] = (_Float16)W[(size_t)k * 192 + n];
}

// ---------------------------------------------------------------------------
// One-time Set2Set LSTM weight prep: k-block row-major f16 (coalesced).
// ---------------------------------------------------------------------------
__global__ __launch_bounds__(256)
void prep_s2sw_kernel(const float* __restrict__ lWi0, const float* __restrict__ lWh0,
                      const float* __restrict__ lWi1, const float* __restrict__ lWh1,
                      const float* __restrict__ lWi2, const float* __restrict__ lWh2,
                      _Float16* __restrict__ WB0, _Float16* __restrict__ WB1,
                      _Float16* __restrict__ WB2)
{
    int idx = blockIdx.x * 256 + threadIdx.x;   // 114688 total
    if (idx < 49152) {
        int k = idx >> 8, n = idx & 255;
        float v = (k < 128) ? lWi0[(size_t)k * 256 + n] : lWh0[(size_t)(k - 128) * 256 + n];
        WB0[((k >> 3) * 2048) + n * 8 + (k & 7)] = (_Float16)v;
    } else if (idx < 81920) {
        int r = idx - 49152;
        int k = r >> 8, n = r & 255;
        float v = (k < 64) ? lWi1[(size_t)k * 256 + n] : lWh1[(size_t)(k - 64) * 256 + n];
        WB1[((k >> 3) * 2048) + n * 8 + (k & 7)] = (_Float16)v;
    } else if (idx < 114688) {
        int r = idx - 81920;
        int k = r >> 8, n = r & 255;
        float v = (k < 64) ? lWi2[(size_t)k * 256 + n] : lWh2[(size_t)(k - 64) * 256 + n];
        WB2[((k >> 3) * 2048) + n * 8 + (k & 7)] = (_Float16)v;
    }
}

// ---------------------------------------------------------------------------
// MFMA NNConv message (f16), 3-deep pipeline, ONE barrier per chunk.
// Round-10: 4 blocks/CU (LDS 33.5KB x4 = 134KB < 160KB) + DUAL accumulator
// chains (s=0,1 -> acc0; s=2,3 -> acc1) to halve the dependent-MFMA chain.
// ---------------------------------------------------------------------------
__global__ __launch_bounds__(256, 4)
void msg_mfma_kernel(const _Float16* __restrict__ t16, const _Float16* __restrict__ h16,
                     const int* __restrict__ src, const int* __restrict__ dst,
                     const unsigned short* __restrict__ w_staged,
                     float* __restrict__ msum, int E)
{
    __shared__ _Float16 tS[64 * 70];                          // [k][e+pad]
    __shared__ __align__(16) unsigned short bbuf[3][4096];    // 3 x 8KB chunks

    const int tid  = threadIdx.x;
    const int lane = tid & 63;
    const int wave = tid >> 6;
    const int wm   = wave & 1, wn = wave >> 1;
    const int e0   = blockIdx.x * 64;

    #pragma unroll
    for (int p = 0; p < 2; ++p) {
        int slot = tid + p * 256;               // 0..511
        int e = slot >> 3, k0 = (slot & 7) * 8;
        int ee = e0 + e;
        half8v tv8 = (half8v)(_Float16)0.f;
        if (ee < E) tv8 = ((const half8v*)(t16 + (size_t)ee * 64))[slot & 7];
        #pragma unroll
        for (int j = 0; j < 8; ++j)
            tS[(k0 + j) * 70 + e] = tv8[j];
    }

    const int erow = wm * 32 + (lane & 31);
    const int ee   = e0 + erow;
    const int sidx = (ee < E) ? src[ee] : 0;
    const half8v* hp = (const half8v*)(h16 + (size_t)sidx * 64);
    half8v Hh[4];
    #pragma unroll
    for (int s = 0; s < 4; ++s)
        Hh[s] = hp[s * 2 + (lane >> 5)];

    const uint4* wsrc = (const uint4*)w_staged;
    {
        uint4 c00 = wsrc[tid], c01 = wsrc[256 + tid];
        ((uint4*)bbuf[0])[tid]       = c00;
        ((uint4*)bbuf[0])[256 + tid] = c01;
    }
    uint4 pA0 = wsrc[512 + tid],  pA1 = wsrc[512 + 256 + tid];    // chunk 1
    uint4 pB0 = wsrc[1024 + tid], pB1 = wsrc[1024 + 256 + tid];   // chunk 2

    f32x16 acc0, acc1;
    #pragma unroll
    for (int r = 0; r < 16; ++r) { acc0[r] = 0.f; acc1[r] = 0.f; }

    const int colg  = wn * 32 + (lane & 31);
    const int bbase = (colg * 128) ^ ((colg & 7) << 4);

    __syncthreads();   // buf0 + tS visible

    int cur = 0;
    for (int kc = 0; kc < 65; ++kc) {
        const _Float16 tv = (kc < 64) ? tS[kc * 70 + erow] : (_Float16)1.0f;
        const char* bb = (const char*)bbuf[cur];
        // two independent accumulation chains (s0,s2 -> acc0; s1,s3 -> acc1)
        {
            half8v af0 = Hh[0] * tv;
            half8v bf0 = *(const half8v*)(bb + (bbase + 0 * 32 + (lane >> 5) * 16));
            half8v af1 = Hh[1] * tv;
            half8v bf1 = *(const half8v*)(bb + (bbase + 1 * 32 + (lane >> 5) * 16));
            acc0 = __builtin_amdgcn_mfma_f32_32x32x16_f16(af0, bf0, acc0, 0, 0, 0);
            acc1 = __builtin_amdgcn_mfma_f32_32x32x16_f16(af1, bf1, acc1, 0, 0, 0);
            half8v af2 = Hh[2] * tv;
            half8v bf2 = *(const half8v*)(bb + (bbase + 2 * 32 + (lane >> 5) * 16));
            half8v af3 = Hh[3] * tv;
            half8v bf3 = *(const half8v*)(bb + (bbase + 3 * 32 + (lane >> 5) * 16));
            acc0 = __builtin_amdgcn_mfma_f32_32x32x16_f16(af2, bf2, acc0, 0, 0, 0);
            acc1 = __builtin_amdgcn_mfma_f32_32x32x16_f16(af3, bf3, acc1, 0, 0, 0);
        }
        const int nxt = (cur == 2) ? 0 : cur + 1;
        if (kc < 64) {
            ((uint4*)bbuf[nxt])[tid]       = pA0;
            ((uint4*)bbuf[nxt])[256 + tid] = pA1;
            pA0 = pB0; pA1 = pB1;
            if (kc + 3 <= 64) {
                pB0 = wsrc[(size_t)(kc + 3) * 512 + tid];
                pB1 = wsrc[(size_t)(kc + 3) * 512 + 256 + tid];
            }
        }
        __syncthreads();
        cur = nxt;
    }

    #pragma unroll
    for (int r = 0; r < 16; ++r) {
        const int row  = (r & 3) + 8 * (r >> 2) + 4 * (lane >> 5);
        const int edge = e0 + wm * 32 + row;
        if (edge < E)
            atomicAdd(&msum[(size_t)dst[edge] * 64 + colg], acc0[r] + acc1[r]);
    }
}

// ---------------------------------------------------------------------------
// MFMA GRU — round-4 known-good version (weights LDS-staged per block).
// ---------------------------------------------------------------------------
__global__ __launch_bounds__(256, 2)
void gru_mfma_kernel(const float* __restrict__ msum, float* __restrict__ h,
                     _Float16* __restrict__ h16,
                     const _Float16* __restrict__ WiT, const _Float16* __restrict__ WhT,
                     const float* __restrict__ bi, const float* __restrict__ bh,
                     const float* __restrict__ conv_b, int N)
{
    __shared__ _Float16 BtI[192 * 72];   // [n][k+pad]
    __shared__ _Float16 BtH[192 * 72];
    __shared__ _Float16 Am[64 * 72];     // [row][k+pad]
    __shared__ _Float16 Ah[64 * 72];

    const int tid  = threadIdx.x;
    const int lane = tid & 63;
    const int wave = tid >> 6;
    const int m0   = wave * 16;
    const int row0 = blockIdx.x * 64;

    #pragma unroll
    for (int p = 0; p < 6; ++p) {
        int slot = tid + p * 256;            // 0..1535
        int n = slot >> 3, k0 = (slot & 7) * 8;
        uint4 vi = ((const uint4*)WiT)[slot];
        uint4 vh = ((const uint4*)WhT)[slot];
        *(uint4*)&BtI[n * 72 + k0] = vi;
        *(uint4*)&BtH[n * 72 + k0] = vh;
    }
    #pragma unroll
    for (int p = 0; p < 4; ++p) {
        int idx = tid + p * 256;             // 0..1023
        int r = idx >> 4, k4 = (idx & 15) * 4;
        int row = row0 + r;
        float4 mv = make_float4(0.f, 0.f, 0.f, 0.f);
        if (row < N) mv = *(const float4*)&msum[(size_t)row * 64 + k4];
        float4 cb = *(const float4*)&conv_b[k4];
        union { _Float16 hx[4]; uint2 u2; } pk;
        pk.hx[0] = (_Float16)fmaxf(mv.x + cb.x, 0.f);
        pk.hx[1] = (_Float16)fmaxf(mv.y + cb.y, 0.f);
        pk.hx[2] = (_Float16)fmaxf(mv.z + cb.z, 0.f);
        pk.hx[3] = (_Float16)fmaxf(mv.w + cb.w, 0.f);
        *(uint2*)&Am[r * 72 + k4] = pk.u2;
    }
    #pragma unroll
    for (int p = 0; p < 2; ++p) {
        int idx = tid + p * 256;             // 0..511
        int r = idx >> 3, k0 = (idx & 7) * 8;
        int row = row0 + r;
        uint4 v = {0u, 0u, 0u, 0u};
        if (row < N) v = *(const uint4*)&h16[(size_t)row * 64 + k0];
        *(uint4*)&Ah[r * 72 + k0] = v;
    }
    __syncthreads();

    const int l15 = lane & 15;

    f32x4 acc_i[12], acc_h[12];
    #pragma unroll
    for (int nt = 0; nt < 12; ++nt) {
        #pragma unroll
        for (int j = 0; j < 4; ++j) { acc_i[nt][j] = 0.f; acc_h[nt][j] = 0.f; }
    }

    #pragma unroll
    for (int ks = 0; ks < 2; ++ks) {
        const int ka = ks * 32 + (lane >> 4) * 8;
        half8v am = *(const half8v*)&Am[(m0 + l15) * 72 + ka];
        half8v ah = *(const half8v*)&Ah[(m0 + l15) * 72 + ka];
        #pragma unroll
        for (int nt = 0; nt < 12; ++nt) {
            half8v b_i = *(const half8v*)&BtI[(nt * 16 + l15) * 72 + ka];
            half8v b_h = *(const half8v*)&BtH[(nt * 16 + l15) * 72 + ka];
            acc_i[nt] = __builtin_amdgcn_mfma_f32_16x16x32_f16(am, b_i, acc_i[nt], 0, 0, 0);
            acc_h[nt] = __builtin_amdgcn_mfma_f32_16x16x32_f16(ah, b_h, acc_h[nt], 0, 0, 0);
        }
    }

    const int rgrp = lane >> 4;
    #pragma unroll
    for (int nt0 = 0; nt0 < 4; ++nt0) {
        const int c = nt0 * 16 + l15;
        const float bir = bi[c],        bhr = bh[c];
        const float biz = bi[64 + c],   bhz = bh[64 + c];
        const float bin = bi[128 + c],  bhn = bh[128 + c];
        #pragma unroll
        for (int j = 0; j < 4; ++j) {
            const int row = row0 + m0 + rgrp * 4 + j;
            if (row >= N) continue;
            float rg = sigf(acc_i[nt0][j]      + bir + acc_h[nt0][j]      + bhr);
            float zg = sigf(acc_i[4 + nt0][j]  + biz + acc_h[4 + nt0][j]  + bhz);
            float ng = tanhf(acc_i[8 + nt0][j] + bin + rg * (acc_h[8 + nt0][j] + bhn));
            float hold = h[(size_t)row * 64 + c];
            float hv = (1.f - zg) * ng + zg * hold;
            h[(size_t)row * 64 + c]   = hv;
            h16[(size_t)row * 64 + c] = (_Float16)hv;
        }
    }
}

// ---------------------------------------------------------------------------
// Per-thread gate dot: k-block row-major f16 weights (coalesced half8v).
// ---------------------------------------------------------------------------
__device__ __forceinline__ float gate_dot8(const _Float16* __restrict__ WB,
                                           int tid, const float* __restrict__ xs,
                                           int nblk)
{
    float a0 = 0.f, a1 = 0.f, a2 = 0.f, a3 = 0.f;
    #pragma unroll 4
    for (int b = 0; b < nblk; ++b) {
        half8v w = *(const half8v*)(WB + (size_t)b * 2048 + tid * 8);
        float4 xa = *(const float4*)&xs[b * 8];
        float4 xb = *(const float4*)&xs[b * 8 + 4];
        a0 = fmaf((float)w[0], xa.x, a0);
        a1 = fmaf((float)w[1], xa.y, a1);
        a2 = fmaf((float)w[2], xa.z, a2);
        a3 = fmaf((float)w[3], xa.w, a3);
        a0 = fmaf((float)w[4], xb.x, a0);
        a1 = fmaf((float)w[5], xb.y, a1);
        a2 = fmaf((float)w[6], xb.z, a2);
        a3 = fmaf((float)w[7], xb.w, a3);
    }
    return (a0 + a1) + (a2 + a3);
}

// ---------------------------------------------------------------------------
// Fused Set2Set + head: 1 graph per block, f16 k-block weights, f32 state.
// ---------------------------------------------------------------------------
__global__ __launch_bounds__(256)
void set2set_kernel(const float* __restrict__ h,
                    const _Float16* __restrict__ WB0, const _Float16* __restrict__ WB1,
                    const _Float16* __restrict__ WB2,
                    const float* __restrict__ lb0, const float* __restrict__ lb1,
                    const float* __restrict__ lb2,
                    const float* __restrict__ pW, const float* __restrict__ pb,
                    const float* __restrict__ fW, const float* __restrict__ fb,
                    float* __restrict__ out)
{
    const int g   = blockIdx.x;
    const int tid = threadIdx.x;

    __shared__ float hl[25 * 65];
    __shared__ float hs[3][64], cs[3][64];
    __shared__ float qstar[128];
    __shared__ __align__(16) float xs[192];
    __shared__ float gates[256];
    __shared__ float als[32];

    for (int idx = tid; idx < 25 * 64; idx += 256) {
        int n = idx >> 6, d = idx & 63;
        hl[n * 65 + d] = h[((size_t)g * 25 + n) * 64 + d];
    }
    if (tid < 128) qstar[tid] = 0.f;
    if (tid < 64) {
        #pragma unroll
        for (int l = 0; l < 3; ++l) { hs[l][tid] = 0.f; cs[l][tid] = 0.f; }
    }
    __syncthreads();

    for (int it = 0; it < 3; ++it) {
        // ---- layer 0 (K = 128 + 64) ----
        if (tid < 128) xs[tid] = qstar[tid];
        else if (tid < 192) xs[tid] = hs[0][tid - 128];
        __syncthreads();
        gates[tid] = lb0[tid] + gate_dot8(WB0, tid, xs, 24);
        __syncthreads();
        if (tid < 64) {
            float ig = sigf(gates[tid]);
            float fg = sigf(gates[64 + tid]);
            float gg = tanhf(gates[128 + tid]);
            float og = sigf(gates[192 + tid]);
            float cv = fg * cs[0][tid] + ig * gg;
            cs[0][tid] = cv;
            hs[0][tid] = og * tanhf(cv);
        }
        __syncthreads();
        // ---- layer 1 (K = 64 + 64) ----
        if (tid < 64) xs[tid] = hs[0][tid];
        else if (tid < 128) xs[tid] = hs[1][tid - 64];
        __syncthreads();
        gates[tid] = lb1[tid] + gate_dot8(WB1, tid, xs, 16);
        __syncthreads();
        if (tid < 64) {
            float ig = sigf(gates[tid]);
            float fg = sigf(gates[64 + tid]);
            float gg = tanhf(gates[128 + tid]);
            float og = sigf(gates[192 + tid]);
            float cv = fg * cs[1][tid] + ig * gg;
            cs[1][tid] = cv;
            hs[1][tid] = og * tanhf(cv);
        }
        __syncthreads();
        // ---- layer 2 (K = 64 + 64) ----
        if (tid < 64) xs[tid] = hs[1][tid];
        else if (tid < 128) xs[tid] = hs[2][tid - 64];
        __syncthreads();
        gates[tid] = lb2[tid] + gate_dot8(WB2, tid, xs, 16);
        __syncthreads();
        if (tid < 64) {
            float ig = sigf(gates[tid]);
            float fg = sigf(gates[64 + tid]);
            float gg = tanhf(gates[128 + tid]);
            float og = sigf(gates[192 + tid]);
            float cv = fg * cs[2][tid] + ig * gg;
            cs[2][tid] = cv;
            hs[2][tid] = og * tanhf(cv);
        }
        __syncthreads();
        // ---- attention over this graph's 25 nodes; q = hs[2] ----
        float ev = -1e30f;
        if (tid < 25) {
            float acc = 0.f;
            for (int d = 0; d < 64; ++d)
                acc = fmaf(hl[tid * 65 + d], hs[2][d], acc);
            ev = acc;
        }
        if (tid < 64) {
            float mx = ev;
            #pragma unroll
            for (int off = 16; off; off >>= 1) mx = fmaxf(mx, __shfl_xor(mx, off, 32));
            float ex = (tid < 25) ? expf(ev - mx) : 0.f;
            float sm = ex;
            #pragma unroll
            for (int off = 16; off; off >>= 1) sm += __shfl_xor(sm, off, 32);
            if (tid < 25) als[tid] = ex / sm;
        }
        __syncthreads();
        if (tid < 64) {
            float rdt = 0.f;
            #pragma unroll
            for (int n = 0; n < 25; ++n) rdt = fmaf(als[n], hl[n * 65 + tid], rdt);
            qstar[tid]      = hs[2][tid];
            qstar[64 + tid] = rdt;
        }
        __syncthreads();
    }

    if (tid < 64) {
        float acc = pb[tid];
        #pragma unroll 8
        for (int k = 0; k < 128; ++k)
            acc = fmaf(qstar[k], pW[(size_t)k * 64 + tid], acc);
        float part = fmaxf(acc, 0.f) * fW[tid];
        #pragma unroll
        for (int off = 32; off; off >>= 1) part += __shfl_xor(part, off, 64);
        if (tid == 0) out[g] = 1.f / (1.f + expf(-(part + fb[0])));
    }
}

// ---------------------------------------------------------------------------
extern "C" void kernel_launch(void* const* d_in, const int* in_sizes, int n_in,
                              void* d_out, int out_size, void* d_ws, size_t ws_size,
                              hipStream_t stream)
{
    const float* n_feats = (const float*)d_in[0];
    const float* e_feats = (const float*)d_in[1];
    const int*   src     = (const int*)d_in[2];
    const int*   dst     = (const int*)d_in[3];
    const float* proj_W  = (const float*)d_in[5];
    const float* proj_b  = (const float*)d_in[6];
    const float* eW1     = (const float*)d_in[7];
    const float* eb1     = (const float*)d_in[8];
    const float* eW2     = (const float*)d_in[9];
    const float* eb2     = (const float*)d_in[10];
    const float* conv_b  = (const float*)d_in[11];
    const float* gWi     = (const float*)d_in[12];
    const float* gWh     = (const float*)d_in[13];
    const float* gbi     = (const float*)d_in[14];
    const float* gbh     = (const float*)d_in[15];
    const float* lWi0    = (const float*)d_in[16];
    const float* lWh0    = (const float*)d_in[17];
    const float* lb0     = (const float*)d_in[18];
    const float* lWi1    = (const float*)d_in[19];
    const float* lWh1    = (const float*)d_in[20];
    const float* lb1     = (const float*)d_in[21];
    const float* lWi2    = (const float*)d_in[22];
    const float* lWh2    = (const float*)d_in[23];
    const float* lb2     = (const float*)d_in[24];
    const float* pW      = (const float*)d_in[25];
    const float* pb      = (const float*)d_in[26];
    const float* fW      = (const float*)d_in[27];
    const float* fb      = (const float*)d_in[28];

    const int N = in_sizes[0] / 74;   // 25000
    const int E = in_sizes[1] / 12;   // 50000
    const int G = out_size;           // 1000

    float* ws   = (float*)d_ws;
    float* h    = ws;                                        // N*64 f32
    float* msum = h + (size_t)N * 64;                        // N*64 f32
    _Float16* h16 = (_Float16*)(msum + (size_t)N * 64);     // N*64 f16
    _Float16* t16 = h16 + (size_t)N * 64;                   // E*64 f16
    unsigned short* w_staged = (unsigned short*)(t16 + (size_t)E * 64); // 65*4096 shorts
    _Float16* WiT = (_Float16*)(w_staged + 65 * 4096);      // 192*64 f16
    _Float16* WhT = WiT + 12288;                            // 192*64 f16
    _Float16* WB0 = WhT + 12288;                            // 192*256 f16
    _Float16* WB1 = WB0 + 49152;                            // 128*256 f16
    _Float16* WB2 = WB1 + 32768;                            // 128*256 f16

    // one-time weight prep
    prep_w_kernel<<<130, 256, 0, stream>>>(eW2, eb2, w_staged);
    prep_gruw_kernel<<<96, 256, 0, stream>>>(gWi, gWh, WiT, WhT);
    prep_s2sw_kernel<<<448, 256, 0, stream>>>(lWi0, lWh0, lWi1, lWh1, lWi2, lWh2,
                                              WB0, WB1, WB2);

    // node projection (h f32 + f16) and edge-net first layer (f16)
    rowmat_relu_t<74, 0><<<(N + 31) / 32, 256, 0, stream>>>(n_feats, proj_W, proj_b, h, h16, N);
    rowmat_relu_t<12, 1><<<(E + 31) / 32, 256, 0, stream>>>(e_feats, eW1, eb1, nullptr, t16, E);

    // 3 rounds of message passing + GRU
    for (int it = 0; it < 3; ++it) {
        hipMemsetAsync(msum, 0, (size_t)N * 64 * sizeof(float), stream);
        msg_mfma_kernel<<<(E + 63) / 64, 256, 0, stream>>>(t16, h16, src, dst, w_staged, msum, E);
        gru_mfma_kernel<<<(N + 63) / 64, 256, 0, stream>>>(msum, h, h16, WiT, WhT,
                                                           gbi, gbh, conv_b, N);
    }

    // fused Set2Set (3 iters) + predict head: 1 graph per block
    set2set_kernel<<<G, 256, 0, stream>>>(h, WB0, WB1, WB2, lb0, lb1, lb2,
                                          pW, pb, fW, fb, (float*)d_out);
}

// Round 11
// 282.104 us; speedup vs baseline: 1.0172x; 1.0172x over previous
//
#include <hip/hip_runtime.h>
#include <math.h>

__device__ __forceinline__ float sigf(float x) { return 1.f / (1.f + expf(-x)); }

using half8v = __attribute__((ext_vector_type(8))) _Float16;
using f32x4  = __attribute__((ext_vector_type(4))) float;

__device__ __forceinline__ unsigned short f2h(float x) {
    union { _Float16 h; unsigned short u; } c; c.h = (_Float16)x; return c.u;
}

// ---------------------------------------------------------------------------
// Templated row-matmul+ReLU (round-9 validated: unroll-2, launch_bounds(,4)).
// ---------------------------------------------------------------------------
template<int K, int MODE>
__global__ __launch_bounds__(256, 4)
void rowmat_relu_t(const float* __restrict__ in, const float* __restrict__ W,
                   const float* __restrict__ b, float* __restrict__ out32,
                   _Float16* __restrict__ out16, int R)
{
    __shared__ float Wl[K * 64];
    __shared__ float rowsS[32 * K];

    const int tid  = threadIdx.x;
    const int row0 = blockIdx.x * 32;

    for (int i = tid; i < K * 64; i += 256)
        Wl[i] = W[i];
    const int lim = (R - row0 >= 32 ? 32 : (R - row0)) * K;
    for (int i = tid; i < 32 * K; i += 256)
        rowsS[i] = (i < lim) ? in[(size_t)row0 * K + i] : 0.f;
    __syncthreads();

    const int wave = tid >> 6, lane = tid & 63;
    const float bv = b[lane];

    float acc[8];
    #pragma unroll
    for (int rr = 0; rr < 8; ++rr) acc[rr] = bv;

    #pragma unroll 2
    for (int k = 0; k < K; ++k) {
        const float wv = Wl[k * 64 + lane];
        #pragma unroll
        for (int rr = 0; rr < 8; ++rr)
            acc[rr] = fmaf(rowsS[(wave * 8 + rr) * K + k], wv, acc[rr]);
    }

    #pragma unroll
    for (int rr = 0; rr < 8; ++rr) {
        const int row = row0 + wave * 8 + rr;
        if (row < R) {
            const float v = fmaxf(acc[rr], 0.f);
            if (MODE == 0) out32[(size_t)row * 64 + lane] = v;
            out16[(size_t)row * 64 + lane] = (_Float16)v;
        }
    }
}

// ---------------------------------------------------------------------------
// One-time edge-net weight prep (f16, swizzled, chunk-major) — validated.
// ---------------------------------------------------------------------------
__global__ __launch_bounds__(256)
void prep_w_kernel(const float* __restrict__ eW2, const float* __restrict__ eb2,
                   unsigned short* __restrict__ w_staged)
{
    int slot = blockIdx.x * 256 + threadIdx.x;     // 65*512 slots
    if (slot >= 65 * 512) return;
    int kc  = slot >> 9;
    int s   = slot & 511;
    int o   = s >> 3, seg = s & 7;
    unsigned int packed[4];
    #pragma unroll
    for (int p = 0; p < 4; ++p) {
        int j0 = kc * 64 + seg * 8 + p * 2;
        float v0 = (j0     < 4096) ? eW2[(size_t)j0 * 64 + o]       : eb2[(size_t)(j0 - 4096) * 64 + o];
        float v1 = (j0 + 1 < 4096) ? eW2[(size_t)(j0 + 1) * 64 + o] : eb2[(size_t)(j0 + 1 - 4096) * 64 + o];
        packed[p] = (unsigned int)f2h(v0) | ((unsigned int)f2h(v1) << 16);
    }
    int dstb = ((o * 128) + seg * 16) ^ ((o & 7) << 4);
    uint4 st = {packed[0], packed[1], packed[2], packed[3]};
    *(uint4*)((char*)w_staged + (size_t)kc * 8192 + dstb) = st;
}

// ---------------------------------------------------------------------------
// One-time GRU weight prep: WiT/WhT[n][k] = (f16) W[k*192+n].
// ---------------------------------------------------------------------------
__global__ __launch_bounds__(256)
void prep_gruw_kernel(const float* __restrict__ Wi, const float* __restrict__ Wh,
                      _Float16* __restrict__ WiT, _Float16* __restrict__ WhT)
{
    int idx = blockIdx.x * 256 + threadIdx.x;
    if (idx >= 2 * 12288) return;
    const float* W = (idx < 12288) ? Wi : Wh;
    _Float16*    O = (idx < 12288) ? WiT : WhT;
    int r = idx & 12287;
    int n = r >> 6, k = r & 63;
    O[n * 64 + k] = (_Float16)W[(size_t)k * 192 + n];
}

// ---------------------------------------------------------------------------
// One-time Set2Set LSTM weight prep: k-block row-major f16 (coalesced).
// ---------------------------------------------------------------------------
__global__ __launch_bounds__(256)
void prep_s2sw_kernel(const float* __restrict__ lWi0, const float* __restrict__ lWh0,
                      const float* __restrict__ lWi1, const float* __restrict__ lWh1,
                      const float* __restrict__ lWi2, const float* __restrict__ lWh2,
                      _Float16* __restrict__ WB0, _Float16* __restrict__ WB1,
                      _Float16* __restrict__ WB2)
{
    int idx = blockIdx.x * 256 + threadIdx.x;   // 114688 total
    if (idx < 49152) {
        int k = idx >> 8, n = idx & 255;
        float v = (k < 128) ? lWi0[(size_t)k * 256 + n] : lWh0[(size_t)(k - 128) * 256 + n];
        WB0[((k >> 3) * 2048) + n * 8 + (k & 7)] = (_Float16)v;
    } else if (idx < 81920) {
        int r = idx - 49152;
        int k = r >> 8, n = r & 255;
        float v = (k < 64) ? lWi1[(size_t)k * 256 + n] : lWh1[(size_t)(k - 64) * 256 + n];
        WB1[((k >> 3) * 2048) + n * 8 + (k & 7)] = (_Float16)v;
    } else if (idx < 114688) {
        int r = idx - 81920;
        int k = r >> 8, n = r & 255;
        float v = (k < 64) ? lWi2[(size_t)k * 256 + n] : lWh2[(size_t)(k - 64) * 256 + n];
        WB2[((k >> 3) * 2048) + n * 8 + (k & 7)] = (_Float16)v;
    }
}

// ---------------------------------------------------------------------------
// MFMA NNConv message (f16), 3-deep pipeline, ONE barrier per chunk.
// Round-11: 16x16x32 MFMAs (4-reg acc, short dependency chains) replacing
// 32x32x16 (16-reg acc, long chains). Per wave per chunk: 2x2 tiles of 16x16,
// 8 MFMAs in 4 independent depth-2 chains. Fragment/epilogue layouts mirror
// the round-4-validated gru_mfma kernel. Staging/swizzle/atomics unchanged.
// ---------------------------------------------------------------------------
__global__ __launch_bounds__(256, 4)
void msg_mfma_kernel(const _Float16* __restrict__ t16, const _Float16* __restrict__ h16,
                     const int* __restrict__ src, const int* __restrict__ dst,
                     const unsigned short* __restrict__ w_staged,
                     float* __restrict__ msum, int E)
{
    __shared__ _Float16 tS[64 * 70];                          // [k][e+pad]
    __shared__ __align__(16) unsigned short bbuf[3][4096];    // 3 x 8KB chunks

    const int tid  = threadIdx.x;
    const int lane = tid & 63;
    const int wave = tid >> 6;
    const int wm   = wave & 1, wn = wave >> 1;
    const int e0   = blockIdx.x * 64;

    // stage t tile transposed into tS[k][e] (f16) — unchanged
    #pragma unroll
    for (int p = 0; p < 2; ++p) {
        int slot = tid + p * 256;               // 0..511
        int e = slot >> 3, k0 = (slot & 7) * 8;
        int ee = e0 + e;
        half8v tv8 = (half8v)(_Float16)0.f;
        if (ee < E) tv8 = ((const half8v*)(t16 + (size_t)ee * 64))[slot & 7];
        #pragma unroll
        for (int j = 0; j < 8; ++j)
            tS[(k0 + j) * 70 + e] = tv8[j];
    }

    const int l15 = lane & 15;
    const int kg  = lane >> 4;          // 0..3

    // resident h16 A-fragments: tile tm row = wm*32 + tm*16 + l15,
    // k-slice = kg*8 + ks*32  (gru-validated 16x16x32 A layout)
    half8v Hh[2][2];
    #pragma unroll
    for (int tm = 0; tm < 2; ++tm) {
        const int edge = e0 + wm * 32 + tm * 16 + l15;
        const int sidx = (edge < E) ? src[edge] : 0;
        const half8v* hp = (const half8v*)(h16 + (size_t)sidx * 64);
        Hh[tm][0] = hp[kg];
        Hh[tm][1] = hp[kg + 4];
    }

    // B-fragment byte offsets: col o = wn*32 + tn*16 + l15, seg = kg + ks*4
    int bofs[2][2];
    #pragma unroll
    for (int tn = 0; tn < 2; ++tn) {
        const int o = wn * 32 + tn * 16 + l15;
        #pragma unroll
        for (int ks = 0; ks < 2; ++ks) {
            const int seg = kg + ks * 4;
            bofs[tn][ks] = (o * 128 + seg * 16) ^ ((o & 7) << 4);
        }
    }

    // prologue: chunk0 -> LDS buf0; chunks 1,2 -> register sets A,B
    const uint4* wsrc = (const uint4*)w_staged;
    {
        uint4 c00 = wsrc[tid], c01 = wsrc[256 + tid];
        ((uint4*)bbuf[0])[tid]       = c00;
        ((uint4*)bbuf[0])[256 + tid] = c01;
    }
    uint4 pA0 = wsrc[512 + tid],  pA1 = wsrc[512 + 256 + tid];    // chunk 1
    uint4 pB0 = wsrc[1024 + tid], pB1 = wsrc[1024 + 256 + tid];   // chunk 2

    f32x4 acc[2][2];
    #pragma unroll
    for (int tm = 0; tm < 2; ++tm)
        #pragma unroll
        for (int tn = 0; tn < 2; ++tn)
            #pragma unroll
            for (int j = 0; j < 4; ++j) acc[tm][tn][j] = 0.f;

    __syncthreads();   // buf0 + tS visible

    int cur = 0;
    for (int kc = 0; kc < 65; ++kc) {
        const char* bb = (const char*)bbuf[cur];
        _Float16 tv0 = (_Float16)1.0f, tv1 = (_Float16)1.0f;
        if (kc < 64) {
            tv0 = tS[kc * 70 + wm * 32 + l15];
            tv1 = tS[kc * 70 + wm * 32 + 16 + l15];
        }
        // A-frags scaled per tile; 8 MFMAs in 4 independent depth-2 chains
        half8v af00 = Hh[0][0] * tv0, af01 = Hh[0][1] * tv0;
        half8v af10 = Hh[1][0] * tv1, af11 = Hh[1][1] * tv1;
        half8v bf00 = *(const half8v*)(bb + bofs[0][0]);
        half8v bf01 = *(const half8v*)(bb + bofs[0][1]);
        half8v bf10 = *(const half8v*)(bb + bofs[1][0]);
        half8v bf11 = *(const half8v*)(bb + bofs[1][1]);
        acc[0][0] = __builtin_amdgcn_mfma_f32_16x16x32_f16(af00, bf00, acc[0][0], 0, 0, 0);
        acc[0][1] = __builtin_amdgcn_mfma_f32_16x16x32_f16(af00, bf10, acc[0][1], 0, 0, 0);
        acc[1][0] = __builtin_amdgcn_mfma_f32_16x16x32_f16(af10, bf00, acc[1][0], 0, 0, 0);
        acc[1][1] = __builtin_amdgcn_mfma_f32_16x16x32_f16(af10, bf10, acc[1][1], 0, 0, 0);
        acc[0][0] = __builtin_amdgcn_mfma_f32_16x16x32_f16(af01, bf01, acc[0][0], 0, 0, 0);
        acc[0][1] = __builtin_amdgcn_mfma_f32_16x16x32_f16(af01, bf11, acc[0][1], 0, 0, 0);
        acc[1][0] = __builtin_amdgcn_mfma_f32_16x16x32_f16(af11, bf01, acc[1][0], 0, 0, 0);
        acc[1][1] = __builtin_amdgcn_mfma_f32_16x16x32_f16(af11, bf11, acc[1][1], 0, 0, 0);

        const int nxt = (cur == 2) ? 0 : cur + 1;
        if (kc < 64) {
            ((uint4*)bbuf[nxt])[tid]       = pA0;
            ((uint4*)bbuf[nxt])[256 + tid] = pA1;
            pA0 = pB0; pA1 = pB1;
            if (kc + 3 <= 64) {
                pB0 = wsrc[(size_t)(kc + 3) * 512 + tid];
                pB1 = wsrc[(size_t)(kc + 3) * 512 + 256 + tid];
            }
        }
        __syncthreads();
        cur = nxt;
    }

    // epilogue: 16x16 C layout (gru-validated): col=l15, row=kg*4+j
    #pragma unroll
    for (int tm = 0; tm < 2; ++tm) {
        #pragma unroll
        for (int j = 0; j < 4; ++j) {
            const int edge = e0 + wm * 32 + tm * 16 + kg * 4 + j;
            if (edge >= E) continue;
            const int d = dst[edge];
            #pragma unroll
            for (int tn = 0; tn < 2; ++tn)
                atomicAdd(&msum[(size_t)d * 64 + wn * 32 + tn * 16 + l15], acc[tm][tn][j]);
        }
    }
}

// ---------------------------------------------------------------------------
// MFMA GRU — round-4 known-good version (weights LDS-staged per block).
// ---------------------------------------------------------------------------
__global__ __launch_bounds__(256, 2)
void gru_mfma_kernel(const float* __restrict__ msum, float* __restrict__ h,
                     _Float16* __restrict__ h16,
                     const _Float16* __restrict__ WiT, const _Float16* __restrict__ WhT,
                     const float* __restrict__ bi, const float* __restrict__ bh,
                     const float* __restrict__ conv_b, int N)
{
    __shared__ _Float16 BtI[192 * 72];   // [n][k+pad]
    __shared__ _Float16 BtH[192 * 72];
    __shared__ _Float16 Am[64 * 72];     // [row][k+pad]
    __shared__ _Float16 Ah[64 * 72];

    const int tid  = threadIdx.x;
    const int lane = tid & 63;
    const int wave = tid >> 6;
    const int m0   = wave * 16;
    const int row0 = blockIdx.x * 64;

    #pragma unroll
    for (int p = 0; p < 6; ++p) {
        int slot = tid + p * 256;            // 0..1535
        int n = slot >> 3, k0 = (slot & 7) * 8;
        uint4 vi = ((const uint4*)WiT)[slot];
        uint4 vh = ((const uint4*)WhT)[slot];
        *(uint4*)&BtI[n * 72 + k0] = vi;
        *(uint4*)&BtH[n * 72 + k0] = vh;
    }
    #pragma unroll
    for (int p = 0; p < 4; ++p) {
        int idx = tid + p * 256;             // 0..1023
        int r = idx >> 4, k4 = (idx & 15) * 4;
        int row = row0 + r;
        float4 mv = make_float4(0.f, 0.f, 0.f, 0.f);
        if (row < N) mv = *(const float4*)&msum[(size_t)row * 64 + k4];
        float4 cb = *(const float4*)&conv_b[k4];
        union { _Float16 hx[4]; uint2 u2; } pk;
        pk.hx[0] = (_Float16)fmaxf(mv.x + cb.x, 0.f);
        pk.hx[1] = (_Float16)fmaxf(mv.y + cb.y, 0.f);
        pk.hx[2] = (_Float16)fmaxf(mv.z + cb.z, 0.f);
        pk.hx[3] = (_Float16)fmaxf(mv.w + cb.w, 0.f);
        *(uint2*)&Am[r * 72 + k4] = pk.u2;
    }
    #pragma unroll
    for (int p = 0; p < 2; ++p) {
        int idx = tid + p * 256;             // 0..511
        int r = idx >> 3, k0 = (idx & 7) * 8;
        int row = row0 + r;
        uint4 v = {0u, 0u, 0u, 0u};
        if (row < N) v = *(const uint4*)&h16[(size_t)row * 64 + k0];
        *(uint4*)&Ah[r * 72 + k0] = v;
    }
    __syncthreads();

    const int l15 = lane & 15;

    f32x4 acc_i[12], acc_h[12];
    #pragma unroll
    for (int nt = 0; nt < 12; ++nt) {
        #pragma unroll
        for (int j = 0; j < 4; ++j) { acc_i[nt][j] = 0.f; acc_h[nt][j] = 0.f; }
    }

    #pragma unroll
    for (int ks = 0; ks < 2; ++ks) {
        const int ka = ks * 32 + (lane >> 4) * 8;
        half8v am = *(const half8v*)&Am[(m0 + l15) * 72 + ka];
        half8v ah = *(const half8v*)&Ah[(m0 + l15) * 72 + ka];
        #pragma unroll
        for (int nt = 0; nt < 12; ++nt) {
            half8v b_i = *(const half8v*)&BtI[(nt * 16 + l15) * 72 + ka];
            half8v b_h = *(const half8v*)&BtH[(nt * 16 + l15) * 72 + ka];
            acc_i[nt] = __builtin_amdgcn_mfma_f32_16x16x32_f16(am, b_i, acc_i[nt], 0, 0, 0);
            acc_h[nt] = __builtin_amdgcn_mfma_f32_16x16x32_f16(ah, b_h, acc_h[nt], 0, 0, 0);
        }
    }

    const int rgrp = lane >> 4;
    #pragma unroll
    for (int nt0 = 0; nt0 < 4; ++nt0) {
        const int c = nt0 * 16 + l15;
        const float bir = bi[c],        bhr = bh[c];
        const float biz = bi[64 + c],   bhz = bh[64 + c];
        const float bin = bi[128 + c],  bhn = bh[128 + c];
        #pragma unroll
        for (int j = 0; j < 4; ++j) {
            const int row = row0 + m0 + rgrp * 4 + j;
            if (row >= N) continue;
            float rg = sigf(acc_i[nt0][j]      + bir + acc_h[nt0][j]      + bhr);
            float zg = sigf(acc_i[4 + nt0][j]  + biz + acc_h[4 + nt0][j]  + bhz);
            float ng = tanhf(acc_i[8 + nt0][j] + bin + rg * (acc_h[8 + nt0][j] + bhn));
            float hold = h[(size_t)row * 64 + c];
            float hv = (1.f - zg) * ng + zg * hold;
            h[(size_t)row * 64 + c]   = hv;
            h16[(size_t)row * 64 + c] = (_Float16)hv;
        }
    }
}

// ---------------------------------------------------------------------------
// Per-thread gate dot: k-block row-major f16 weights (coalesced half8v).
// ---------------------------------------------------------------------------
__device__ __forceinline__ float gate_dot8(const _Float16* __restrict__ WB,
                                           int tid, const float* __restrict__ xs,
                                           int nblk)
{
    float a0 = 0.f, a1 = 0.f, a2 = 0.f, a3 = 0.f;
    #pragma unroll 4
    for (int b = 0; b < nblk; ++b) {
        half8v w = *(const half8v*)(WB + (size_t)b * 2048 + tid * 8);
        float4 xa = *(const float4*)&xs[b * 8];
        float4 xb = *(const float4*)&xs[b * 8 + 4];
        a0 = fmaf((float)w[0], xa.x, a0);
        a1 = fmaf((float)w[1], xa.y, a1);
        a2 = fmaf((float)w[2], xa.z, a2);
        a3 = fmaf((float)w[3], xa.w, a3);
        a0 = fmaf((float)w[4], xb.x, a0);
        a1 = fmaf((float)w[5], xb.y, a1);
        a2 = fmaf((float)w[6], xb.z, a2);
        a3 = fmaf((float)w[7], xb.w, a3);
    }
    return (a0 + a1) + (a2 + a3);
}

// ---------------------------------------------------------------------------
// Fused Set2Set + head: 1 graph per block, f16 k-block weights, f32 state.
// ---------------------------------------------------------------------------
__global__ __launch_bounds__(256)
void set2set_kernel(const float* __restrict__ h,
                    const _Float16* __restrict__ WB0, const _Float16* __restrict__ WB1,
                    const _Float16* __restrict__ WB2,
                    const float* __restrict__ lb0, const float* __restrict__ lb1,
                    const float* __restrict__ lb2,
                    const float* __restrict__ pW, const float* __restrict__ pb,
                    const float* __restrict__ fW, const float* __restrict__ fb,
                    float* __restrict__ out)
{
    const int g   = blockIdx.x;
    const int tid = threadIdx.x;

    __shared__ float hl[25 * 65];
    __shared__ float hs[3][64], cs[3][64];
    __shared__ float qstar[128];
    __shared__ __align__(16) float xs[192];
    __shared__ float gates[256];
    __shared__ float als[32];

    for (int idx = tid; idx < 25 * 64; idx += 256) {
        int n = idx >> 6, d = idx & 63;
        hl[n * 65 + d] = h[((size_t)g * 25 + n) * 64 + d];
    }
    if (tid < 128) qstar[tid] = 0.f;
    if (tid < 64) {
        #pragma unroll
        for (int l = 0; l < 3; ++l) { hs[l][tid] = 0.f; cs[l][tid] = 0.f; }
    }
    __syncthreads();

    for (int it = 0; it < 3; ++it) {
        // ---- layer 0 (K = 128 + 64) ----
        if (tid < 128) xs[tid] = qstar[tid];
        else if (tid < 192) xs[tid] = hs[0][tid - 128];
        __syncthreads();
        gates[tid] = lb0[tid] + gate_dot8(WB0, tid, xs, 24);
        __syncthreads();
        if (tid < 64) {
            float ig = sigf(gates[tid]);
            float fg = sigf(gates[64 + tid]);
            float gg = tanhf(gates[128 + tid]);
            float og = sigf(gates[192 + tid]);
            float cv = fg * cs[0][tid] + ig * gg;
            cs[0][tid] = cv;
            hs[0][tid] = og * tanhf(cv);
        }
        __syncthreads();
        // ---- layer 1 (K = 64 + 64) ----
        if (tid < 64) xs[tid] = hs[0][tid];
        else if (tid < 128) xs[tid] = hs[1][tid - 64];
        __syncthreads();
        gates[tid] = lb1[tid] + gate_dot8(WB1, tid, xs, 16);
        __syncthreads();
        if (tid < 64) {
            float ig = sigf(gates[tid]);
            float fg = sigf(gates[64 + tid]);
            float gg = tanhf(gates[128 + tid]);
            float og = sigf(gates[192 + tid]);
            float cv = fg * cs[1][tid] + ig * gg;
            cs[1][tid] = cv;
            hs[1][tid] = og * tanhf(cv);
        }
        __syncthreads();
        // ---- layer 2 (K = 64 + 64) ----
        if (tid < 64) xs[tid] = hs[1][tid];
        else if (tid < 128) xs[tid] = hs[2][tid - 64];
        __syncthreads();
        gates[tid] = lb2[tid] + gate_dot8(WB2, tid, xs, 16);
        __syncthreads();
        if (tid < 64) {
            float ig = sigf(gates[tid]);
            float fg = sigf(gates[64 + tid]);
            float gg = tanhf(gates[128 + tid]);
            float og = sigf(gates[192 + tid]);
            float cv = fg * cs[2][tid] + ig * gg;
            cs[2][tid] = cv;
            hs[2][tid] = og * tanhf(cv);
        }
        __syncthreads();
        // ---- attention over this graph's 25 nodes; q = hs[2] ----
        float ev = -1e30f;
        if (tid < 25) {
            float acc = 0.f;
            for (int d = 0; d < 64; ++d)
                acc = fmaf(hl[tid * 65 + d], hs[2][d], acc);
            ev = acc;
        }
        if (tid < 64) {
            float mx = ev;
            #pragma unroll
            for (int off = 16; off; off >>= 1) mx = fmaxf(mx, __shfl_xor(mx, off, 32));
            float ex = (tid < 25) ? expf(ev - mx) : 0.f;
            float sm = ex;
            #pragma unroll
            for (int off = 16; off; off >>= 1) sm += __shfl_xor(sm, off, 32);
            if (tid < 25) als[tid] = ex / sm;
        }
        __syncthreads();
        if (tid < 64) {
            float rdt = 0.f;
            #pragma unroll
            for (int n = 0; n < 25; ++n) rdt = fmaf(als[n], hl[n * 65 + tid], rdt);
            qstar[tid]      = hs[2][tid];
            qstar[64 + tid] = rdt;
        }
        __syncthreads();
    }

    if (tid < 64) {
        float acc = pb[tid];
        #pragma unroll 8
        for (int k = 0; k < 128; ++k)
            acc = fmaf(qstar[k], pW[(size_t)k * 64 + tid], acc);
        float part = fmaxf(acc, 0.f) * fW[tid];
        #pragma unroll
        for (int off = 32; off; off >>= 1) part += __shfl_xor(part, off, 64);
        if (tid == 0) out[g] = 1.f / (1.f + expf(-(part + fb[0])));
    }
}

// ---------------------------------------------------------------------------
extern "C" void kernel_launch(void* const* d_in, const int* in_sizes, int n_in,
                              void* d_out, int out_size, void* d_ws, size_t ws_size,
                              hipStream_t stream)
{
    const float* n_feats = (const float*)d_in[0];
    const float* e_feats = (const float*)d_in[1];
    const int*   src     = (const int*)d_in[2];
    const int*   dst     = (const int*)d_in[3];
    const float* proj_W  = (const float*)d_in[5];
    const float* proj_b  = (const float*)d_in[6];
    const float* eW1     = (const float*)d_in[7];
    const float* eb1     = (const float*)d_in[8];
    const float* eW2     = (const float*)d_in[9];
    const float* eb2     = (const float*)d_in[10];
    const float* conv_b  = (const float*)d_in[11];
    const float* gWi     = (const float*)d_in[12];
    const float* gWh     = (const float*)d_in[13];
    const float* gbi     = (const float*)d_in[14];
    const float* gbh     = (const float*)d_in[15];
    const float* lWi0    = (const float*)d_in[16];
    const float* lWh0    = (const float*)d_in[17];
    const float* lb0     = (const float*)d_in[18];
    const float* lWi1    = (const float*)d_in[19];
    const float* lWh1    = (const float*)d_in[20];
    const float* lb1     = (const float*)d_in[21];
    const float* lWi2    = (const float*)d_in[22];
    const float* lWh2    = (const float*)d_in[23];
    const float* lb2     = (const float*)d_in[24];
    const float* pW      = (const float*)d_in[25];
    const float* pb      = (const float*)d_in[26];
    const float* fW      = (const float*)d_in[27];
    const float* fb      = (const float*)d_in[28];

    const int N = in_sizes[0] / 74;   // 25000
    const int E = in_sizes[1] / 12;   // 50000
    const int G = out_size;           // 1000

    float* ws   = (float*)d_ws;
    float* h    = ws;                                        // N*64 f32
    float* msum = h + (size_t)N * 64;                        // N*64 f32
    _Float16* h16 = (_Float16*)(msum + (size_t)N * 64);     // N*64 f16
    _Float16* t16 = h16 + (size_t)N * 64;                   // E*64 f16
    unsigned short* w_staged = (unsigned short*)(t16 + (size_t)E * 64); // 65*4096 shorts
    _Float16* WiT = (_Float16*)(w_staged + 65 * 4096);      // 192*64 f16
    _Float16* WhT = WiT + 12288;                            // 192*64 f16
    _Float16* WB0 = WhT + 12288;                            // 192*256 f16
    _Float16* WB1 = WB0 + 49152;                            // 128*256 f16
    _Float16* WB2 = WB1 + 32768;                            // 128*256 f16

    // one-time weight prep
    prep_w_kernel<<<130, 256, 0, stream>>>(eW2, eb2, w_staged);
    prep_gruw_kernel<<<96, 256, 0, stream>>>(gWi, gWh, WiT, WhT);
    prep_s2sw_kernel<<<448, 256, 0, stream>>>(lWi0, lWh0, lWi1, lWh1, lWi2, lWh2,
                                              WB0, WB1, WB2);

    // node projection (h f32 + f16) and edge-net first layer (f16)
    rowmat_relu_t<74, 0><<<(N + 31) / 32, 256, 0, stream>>>(n_feats, proj_W, proj_b, h, h16, N);
    rowmat_relu_t<12, 1><<<(E + 31) / 32, 256, 0, stream>>>(e_feats, eW1, eb1, nullptr, t16, E);

    // 3 rounds of message passing + GRU
    for (int it = 0; it < 3; ++it) {
        hipMemsetAsync(msum, 0, (size_t)N * 64 * sizeof(float), stream);
        msg_mfma_kernel<<<(E + 63) / 64, 256, 0, stream>>>(t16, h16, src, dst, w_staged, msum, E);
        gru_mfma_kernel<<<(N + 63) / 64, 256, 0, stream>>>(msum, h, h16, WiT, WhT,
                                                           gbi, gbh, conv_b, N);
    }

    // fused Set2Set (3 iters) + predict head: 1 graph per block
    set2set_kernel<<<G, 256, 0, stream>>>(h, WB0, WB1, WB2, lb0, lb1, lb2,
                                          pW, pb, fW, fb, (float*)d_out);
}

// Round 12
// 280.562 us; speedup vs baseline: 1.0228x; 1.0055x over previous
//
#include <hip/hip_runtime.h>
#include <math.h>

__device__ __forceinline__ float sigf(float x) { return 1.f / (1.f + expf(-x)); }

using half8v = __attribute__((ext_vector_type(8))) _Float16;
using f32x4  = __attribute__((ext_vector_type(4))) float;

__device__ __forceinline__ unsigned short f2h(float x) {
    union { _Float16 h; unsigned short u; } c; c.h = (_Float16)x; return c.u;
}

// ---------------------------------------------------------------------------
// Templated row-matmul+ReLU (round-9 validated: unroll-2, launch_bounds(,4)).
// ---------------------------------------------------------------------------
template<int K, int MODE>
__global__ __launch_bounds__(256, 4)
void rowmat_relu_t(const float* __restrict__ in, const float* __restrict__ W,
                   const float* __restrict__ b, float* __restrict__ out32,
                   _Float16* __restrict__ out16, int R)
{
    __shared__ float Wl[K * 64];
    __shared__ float rowsS[32 * K];

    const int tid  = threadIdx.x;
    const int row0 = blockIdx.x * 32;

    for (int i = tid; i < K * 64; i += 256)
        Wl[i] = W[i];
    const int lim = (R - row0 >= 32 ? 32 : (R - row0)) * K;
    for (int i = tid; i < 32 * K; i += 256)
        rowsS[i] = (i < lim) ? in[(size_t)row0 * K + i] : 0.f;
    __syncthreads();

    const int wave = tid >> 6, lane = tid & 63;
    const float bv = b[lane];

    float acc[8];
    #pragma unroll
    for (int rr = 0; rr < 8; ++rr) acc[rr] = bv;

    #pragma unroll 2
    for (int k = 0; k < K; ++k) {
        const float wv = Wl[k * 64 + lane];
        #pragma unroll
        for (int rr = 0; rr < 8; ++rr)
            acc[rr] = fmaf(rowsS[(wave * 8 + rr) * K + k], wv, acc[rr]);
    }

    #pragma unroll
    for (int rr = 0; rr < 8; ++rr) {
        const int row = row0 + wave * 8 + rr;
        if (row < R) {
            const float v = fmaxf(acc[rr], 0.f);
            if (MODE == 0) out32[(size_t)row * 64 + lane] = v;
            out16[(size_t)row * 64 + lane] = (_Float16)v;
        }
    }
}

// ---------------------------------------------------------------------------
// One-time edge-net weight prep (f16, swizzled, chunk-major) — validated.
// ---------------------------------------------------------------------------
__global__ __launch_bounds__(256)
void prep_w_kernel(const float* __restrict__ eW2, const float* __restrict__ eb2,
                   unsigned short* __restrict__ w_staged)
{
    int slot = blockIdx.x * 256 + threadIdx.x;     // 65*512 slots
    if (slot >= 65 * 512) return;
    int kc  = slot >> 9;
    int s   = slot & 511;
    int o   = s >> 3, seg = s & 7;
    unsigned int packed[4];
    #pragma unroll
    for (int p = 0; p < 4; ++p) {
        int j0 = kc * 64 + seg * 8 + p * 2;
        float v0 = (j0     < 4096) ? eW2[(size_t)j0 * 64 + o]       : eb2[(size_t)(j0 - 4096) * 64 + o];
        float v1 = (j0 + 1 < 4096) ? eW2[(size_t)(j0 + 1) * 64 + o] : eb2[(size_t)(j0 + 1 - 4096) * 64 + o];
        packed[p] = (unsigned int)f2h(v0) | ((unsigned int)f2h(v1) << 16);
    }
    int dstb = ((o * 128) + seg * 16) ^ ((o & 7) << 4);
    uint4 st = {packed[0], packed[1], packed[2], packed[3]};
    *(uint4*)((char*)w_staged + (size_t)kc * 8192 + dstb) = st;
}

// ---------------------------------------------------------------------------
// One-time GRU weight prep: WiT/WhT[n][k] = (f16) W[k*192+n].
// ---------------------------------------------------------------------------
__global__ __launch_bounds__(256)
void prep_gruw_kernel(const float* __restrict__ Wi, const float* __restrict__ Wh,
                      _Float16* __restrict__ WiT, _Float16* __restrict__ WhT)
{
    int idx = blockIdx.x * 256 + threadIdx.x;
    if (idx >= 2 * 12288) return;
    const float* W = (idx < 12288) ? Wi : Wh;
    _Float16*    O = (idx < 12288) ? WiT : WhT;
    int r = idx & 12287;
    int n = r >> 6, k = r & 63;
    O[n * 64 + k] = (_Float16)W[(size_t)k * 192 + n];
}

// ---------------------------------------------------------------------------
// One-time Set2Set LSTM weight prep: k-block row-major f16 (coalesced).
// ---------------------------------------------------------------------------
__global__ __launch_bounds__(256)
void prep_s2sw_kernel(const float* __restrict__ lWi0, const float* __restrict__ lWh0,
                      const float* __restrict__ lWi1, const float* __restrict__ lWh1,
                      const float* __restrict__ lWi2, const float* __restrict__ lWh2,
                      _Float16* __restrict__ WB0, _Float16* __restrict__ WB1,
                      _Float16* __restrict__ WB2)
{
    int idx = blockIdx.x * 256 + threadIdx.x;   // 114688 total
    if (idx < 49152) {
        int k = idx >> 8, n = idx & 255;
        float v = (k < 128) ? lWi0[(size_t)k * 256 + n] : lWh0[(size_t)(k - 128) * 256 + n];
        WB0[((k >> 3) * 2048) + n * 8 + (k & 7)] = (_Float16)v;
    } else if (idx < 81920) {
        int r = idx - 49152;
        int k = r >> 8, n = r & 255;
        float v = (k < 64) ? lWi1[(size_t)k * 256 + n] : lWh1[(size_t)(k - 64) * 256 + n];
        WB1[((k >> 3) * 2048) + n * 8 + (k & 7)] = (_Float16)v;
    } else if (idx < 114688) {
        int r = idx - 81920;
        int k = r >> 8, n = r & 255;
        float v = (k < 64) ? lWi2[(size_t)k * 256 + n] : lWh2[(size_t)(k - 64) * 256 + n];
        WB2[((k >> 3) * 2048) + n * 8 + (k & 7)] = (_Float16)v;
    }
}

// ---------------------------------------------------------------------------
// MFMA NNConv message (f16), 3-deep pipeline.
// Round-12: raw s_barrier + lgkmcnt(0)-only wait (T4 counted-vmcnt pattern).
// __syncthreads' implicit vmcnt(0) drain was serializing one L2 round-trip
// per chunk (rounds 9-11 all flat at ~53-55us). Parity registers P0/P1: the
// ds_write's register dependence makes the compiler emit a COUNTED vmcnt
// (newest pair stays in flight across the barrier). Buffer-rotation hazard
// discipline identical to the validated 3-buf scheme.
// ---------------------------------------------------------------------------
__global__ __launch_bounds__(256, 4)
void msg_mfma_kernel(const _Float16* __restrict__ t16, const _Float16* __restrict__ h16,
                     const int* __restrict__ src, const int* __restrict__ dst,
                     const unsigned short* __restrict__ w_staged,
                     float* __restrict__ msum, int E)
{
    __shared__ _Float16 tS[64 * 70];                          // [k][e+pad]
    __shared__ __align__(16) unsigned short bbuf[3][4096];    // 3 x 8KB chunks

    const int tid  = threadIdx.x;
    const int lane = tid & 63;
    const int wave = tid >> 6;
    const int wm   = wave & 1, wn = wave >> 1;
    const int e0   = blockIdx.x * 64;

    // stage t tile transposed into tS[k][e] (f16) — unchanged
    #pragma unroll
    for (int p = 0; p < 2; ++p) {
        int slot = tid + p * 256;               // 0..511
        int e = slot >> 3, k0 = (slot & 7) * 8;
        int ee = e0 + e;
        half8v tv8 = (half8v)(_Float16)0.f;
        if (ee < E) tv8 = ((const half8v*)(t16 + (size_t)ee * 64))[slot & 7];
        #pragma unroll
        for (int j = 0; j < 8; ++j)
            tS[(k0 + j) * 70 + e] = tv8[j];
    }

    const int l15 = lane & 15;
    const int kg  = lane >> 4;          // 0..3

    // resident h16 A-fragments (gru-validated 16x16x32 A layout)
    half8v Hh[2][2];
    #pragma unroll
    for (int tm = 0; tm < 2; ++tm) {
        const int edge = e0 + wm * 32 + tm * 16 + l15;
        const int sidx = (edge < E) ? src[edge] : 0;
        const half8v* hp = (const half8v*)(h16 + (size_t)sidx * 64);
        Hh[tm][0] = hp[kg];
        Hh[tm][1] = hp[kg + 4];
    }

    // B-fragment byte offsets: col o = wn*32 + tn*16 + l15, seg = kg + ks*4
    int bofs[2][2];
    #pragma unroll
    for (int tn = 0; tn < 2; ++tn) {
        const int o = wn * 32 + tn * 16 + l15;
        #pragma unroll
        for (int ks = 0; ks < 2; ++ks) {
            const int seg = kg + ks * 4;
            bofs[tn][ks] = (o * 128 + seg * 16) ^ ((o & 7) << 4);
        }
    }

    // prologue: chunk0 -> LDS buf0; chunks 1,2 -> parity register pairs
    const uint4* wsrc = (const uint4*)w_staged;
    {
        uint4 c00 = wsrc[tid], c01 = wsrc[256 + tid];
        ((uint4*)bbuf[0])[tid]       = c00;
        ((uint4*)bbuf[0])[256 + tid] = c01;
    }
    uint4 P00 = wsrc[512 + tid],  P01 = wsrc[512 + 256 + tid];    // chunk 1 (even parity)
    uint4 P10 = wsrc[1024 + tid], P11 = wsrc[1024 + 256 + tid];   // chunk 2 (odd parity)

    f32x4 acc[2][2];
    #pragma unroll
    for (int tm = 0; tm < 2; ++tm)
        #pragma unroll
        for (int tn = 0; tn < 2; ++tn)
            #pragma unroll
            for (int j = 0; j < 4; ++j) acc[tm][tn][j] = 0.f;

    __syncthreads();   // one-time full drain: buf0 + tS visible, P* complete

    int cur = 0;
    for (int kc = 0; kc < 65; ++kc) {
        const char* bb = (const char*)bbuf[cur];
        _Float16 tv0 = (_Float16)1.0f, tv1 = (_Float16)1.0f;
        if (kc < 64) {
            tv0 = tS[kc * 70 + wm * 32 + l15];
            tv1 = tS[kc * 70 + wm * 32 + 16 + l15];
        }
        half8v af00 = Hh[0][0] * tv0, af01 = Hh[0][1] * tv0;
        half8v af10 = Hh[1][0] * tv1, af11 = Hh[1][1] * tv1;
        half8v bf00 = *(const half8v*)(bb + bofs[0][0]);
        half8v bf01 = *(const half8v*)(bb + bofs[0][1]);
        half8v bf10 = *(const half8v*)(bb + bofs[1][0]);
        half8v bf11 = *(const half8v*)(bb + bofs[1][1]);
        acc[0][0] = __builtin_amdgcn_mfma_f32_16x16x32_f16(af00, bf00, acc[0][0], 0, 0, 0);
        acc[0][1] = __builtin_amdgcn_mfma_f32_16x16x32_f16(af00, bf10, acc[0][1], 0, 0, 0);
        acc[1][0] = __builtin_amdgcn_mfma_f32_16x16x32_f16(af10, bf00, acc[1][0], 0, 0, 0);
        acc[1][1] = __builtin_amdgcn_mfma_f32_16x16x32_f16(af10, bf10, acc[1][1], 0, 0, 0);
        acc[0][0] = __builtin_amdgcn_mfma_f32_16x16x32_f16(af01, bf01, acc[0][0], 0, 0, 0);
        acc[0][1] = __builtin_amdgcn_mfma_f32_16x16x32_f16(af01, bf11, acc[0][1], 0, 0, 0);
        acc[1][0] = __builtin_amdgcn_mfma_f32_16x16x32_f16(af11, bf01, acc[1][0], 0, 0, 0);
        acc[1][1] = __builtin_amdgcn_mfma_f32_16x16x32_f16(af11, bf11, acc[1][1], 0, 0, 0);

        const int nxt = (cur == 2) ? 0 : cur + 1;
        if (kc < 64) {
            // write chunk kc+1 (loaded 2 iterations ago -> counted vmcnt wait),
            // then issue chunk kc+3 into the same parity pair.
            if (kc & 1) {
                ((uint4*)bbuf[nxt])[tid]       = P10;
                ((uint4*)bbuf[nxt])[256 + tid] = P11;
                if (kc + 3 <= 64) {
                    P10 = wsrc[(size_t)(kc + 3) * 512 + tid];
                    P11 = wsrc[(size_t)(kc + 3) * 512 + 256 + tid];
                }
            } else {
                ((uint4*)bbuf[nxt])[tid]       = P00;
                ((uint4*)bbuf[nxt])[256 + tid] = P01;
                if (kc + 3 <= 64) {
                    P00 = wsrc[(size_t)(kc + 3) * 512 + tid];
                    P01 = wsrc[(size_t)(kc + 3) * 512 + 256 + tid];
                }
            }
        }
        // T4: drain LDS writes only; global prefetch loads stay in flight.
        asm volatile("s_waitcnt lgkmcnt(0)" ::: "memory");
        __builtin_amdgcn_s_barrier();
        asm volatile("" ::: "memory");
        cur = nxt;
    }

    // epilogue: 16x16 C layout (gru-validated): col=l15, row=kg*4+j
    #pragma unroll
    for (int tm = 0; tm < 2; ++tm) {
        #pragma unroll
        for (int j = 0; j < 4; ++j) {
            const int edge = e0 + wm * 32 + tm * 16 + kg * 4 + j;
            if (edge >= E) continue;
            const int d = dst[edge];
            #pragma unroll
            for (int tn = 0; tn < 2; ++tn)
                atomicAdd(&msum[(size_t)d * 64 + wn * 32 + tn * 16 + l15], acc[tm][tn][j]);
        }
    }
}

// ---------------------------------------------------------------------------
// MFMA GRU — round-4 known-good version (weights LDS-staged per block).
// ---------------------------------------------------------------------------
__global__ __launch_bounds__(256, 2)
void gru_mfma_kernel(const float* __restrict__ msum, float* __restrict__ h,
                     _Float16* __restrict__ h16,
                     const _Float16* __restrict__ WiT, const _Float16* __restrict__ WhT,
                     const float* __restrict__ bi, const float* __restrict__ bh,
                     const float* __restrict__ conv_b, int N)
{
    __shared__ _Float16 BtI[192 * 72];   // [n][k+pad]
    __shared__ _Float16 BtH[192 * 72];
    __shared__ _Float16 Am[64 * 72];     // [row][k+pad]
    __shared__ _Float16 Ah[64 * 72];

    const int tid  = threadIdx.x;
    const int lane = tid & 63;
    const int wave = tid >> 6;
    const int m0   = wave * 16;
    const int row0 = blockIdx.x * 64;

    #pragma unroll
    for (int p = 0; p < 6; ++p) {
        int slot = tid + p * 256;            // 0..1535
        int n = slot >> 3, k0 = (slot & 7) * 8;
        uint4 vi = ((const uint4*)WiT)[slot];
        uint4 vh = ((const uint4*)WhT)[slot];
        *(uint4*)&BtI[n * 72 + k0] = vi;
        *(uint4*)&BtH[n * 72 + k0] = vh;
    }
    #pragma unroll
    for (int p = 0; p < 4; ++p) {
        int idx = tid + p * 256;             // 0..1023
        int r = idx >> 4, k4 = (idx & 15) * 4;
        int row = row0 + r;
        float4 mv = make_float4(0.f, 0.f, 0.f, 0.f);
        if (row < N) mv = *(const float4*)&msum[(size_t)row * 64 + k4];
        float4 cb = *(const float4*)&conv_b[k4];
        union { _Float16 hx[4]; uint2 u2; } pk;
        pk.hx[0] = (_Float16)fmaxf(mv.x + cb.x, 0.f);
        pk.hx[1] = (_Float16)fmaxf(mv.y + cb.y, 0.f);
        pk.hx[2] = (_Float16)fmaxf(mv.z + cb.z, 0.f);
        pk.hx[3] = (_Float16)fmaxf(mv.w + cb.w, 0.f);
        *(uint2*)&Am[r * 72 + k4] = pk.u2;
    }
    #pragma unroll
    for (int p = 0; p < 2; ++p) {
        int idx = tid + p * 256;             // 0..511
        int r = idx >> 3, k0 = (idx & 7) * 8;
        int row = row0 + r;
        uint4 v = {0u, 0u, 0u, 0u};
        if (row < N) v = *(const uint4*)&h16[(size_t)row * 64 + k0];
        *(uint4*)&Ah[r * 72 + k0] = v;
    }
    __syncthreads();

    const int l15 = lane & 15;

    f32x4 acc_i[12], acc_h[12];
    #pragma unroll
    for (int nt = 0; nt < 12; ++nt) {
        #pragma unroll
        for (int j = 0; j < 4; ++j) { acc_i[nt][j] = 0.f; acc_h[nt][j] = 0.f; }
    }

    #pragma unroll
    for (int ks = 0; ks < 2; ++ks) {
        const int ka = ks * 32 + (lane >> 4) * 8;
        half8v am = *(const half8v*)&Am[(m0 + l15) * 72 + ka];
        half8v ah = *(const half8v*)&Ah[(m0 + l15) * 72 + ka];
        #pragma unroll
        for (int nt = 0; nt < 12; ++nt) {
            half8v b_i = *(const half8v*)&BtI[(nt * 16 + l15) * 72 + ka];
            half8v b_h = *(const half8v*)&BtH[(nt * 16 + l15) * 72 + ka];
            acc_i[nt] = __builtin_amdgcn_mfma_f32_16x16x32_f16(am, b_i, acc_i[nt], 0, 0, 0);
            acc_h[nt] = __builtin_amdgcn_mfma_f32_16x16x32_f16(ah, b_h, acc_h[nt], 0, 0, 0);
        }
    }

    const int rgrp = lane >> 4;
    #pragma unroll
    for (int nt0 = 0; nt0 < 4; ++nt0) {
        const int c = nt0 * 16 + l15;
        const float bir = bi[c],        bhr = bh[c];
        const float biz = bi[64 + c],   bhz = bh[64 + c];
        const float bin = bi[128 + c],  bhn = bh[128 + c];
        #pragma unroll
        for (int j = 0; j < 4; ++j) {
            const int row = row0 + m0 + rgrp * 4 + j;
            if (row >= N) continue;
            float rg = sigf(acc_i[nt0][j]      + bir + acc_h[nt0][j]      + bhr);
            float zg = sigf(acc_i[4 + nt0][j]  + biz + acc_h[4 + nt0][j]  + bhz);
            float ng = tanhf(acc_i[8 + nt0][j] + bin + rg * (acc_h[8 + nt0][j] + bhn));
            float hold = h[(size_t)row * 64 + c];
            float hv = (1.f - zg) * ng + zg * hold;
            h[(size_t)row * 64 + c]   = hv;
            h16[(size_t)row * 64 + c] = (_Float16)hv;
        }
    }
}

// ---------------------------------------------------------------------------
// Per-thread gate dot: k-block row-major f16 weights (coalesced half8v).
// ---------------------------------------------------------------------------
__device__ __forceinline__ float gate_dot8(const _Float16* __restrict__ WB,
                                           int tid, const float* __restrict__ xs,
                                           int nblk)
{
    float a0 = 0.f, a1 = 0.f, a2 = 0.f, a3 = 0.f;
    #pragma unroll 4
    for (int b = 0; b < nblk; ++b) {
        half8v w = *(const half8v*)(WB + (size_t)b * 2048 + tid * 8);
        float4 xa = *(const float4*)&xs[b * 8];
        float4 xb = *(const float4*)&xs[b * 8 + 4];
        a0 = fmaf((float)w[0], xa.x, a0);
        a1 = fmaf((float)w[1], xa.y, a1);
        a2 = fmaf((float)w[2], xa.z, a2);
        a3 = fmaf((float)w[3], xa.w, a3);
        a0 = fmaf((float)w[4], xb.x, a0);
        a1 = fmaf((float)w[5], xb.y, a1);
        a2 = fmaf((float)w[6], xb.z, a2);
        a3 = fmaf((float)w[7], xb.w, a3);
    }
    return (a0 + a1) + (a2 + a3);
}

// ---------------------------------------------------------------------------
// Fused Set2Set + head: 1 graph per block, f16 k-block weights, f32 state.
// ---------------------------------------------------------------------------
__global__ __launch_bounds__(256)
void set2set_kernel(const float* __restrict__ h,
                    const _Float16* __restrict__ WB0, const _Float16* __restrict__ WB1,
                    const _Float16* __restrict__ WB2,
                    const float* __restrict__ lb0, const float* __restrict__ lb1,
                    const float* __restrict__ lb2,
                    const float* __restrict__ pW, const float* __restrict__ pb,
                    const float* __restrict__ fW, const float* __restrict__ fb,
                    float* __restrict__ out)
{
    const int g   = blockIdx.x;
    const int tid = threadIdx.x;

    __shared__ float hl[25 * 65];
    __shared__ float hs[3][64], cs[3][64];
    __shared__ float qstar[128];
    __shared__ __align__(16) float xs[192];
    __shared__ float gates[256];
    __shared__ float als[32];

    for (int idx = tid; idx < 25 * 64; idx += 256) {
        int n = idx >> 6, d = idx & 63;
        hl[n * 65 + d] = h[((size_t)g * 25 + n) * 64 + d];
    }
    if (tid < 128) qstar[tid] = 0.f;
    if (tid < 64) {
        #pragma unroll
        for (int l = 0; l < 3; ++l) { hs[l][tid] = 0.f; cs[l][tid] = 0.f; }
    }
    __syncthreads();

    for (int it = 0; it < 3; ++it) {
        // ---- layer 0 (K = 128 + 64) ----
        if (tid < 128) xs[tid] = qstar[tid];
        else if (tid < 192) xs[tid] = hs[0][tid - 128];
        __syncthreads();
        gates[tid] = lb0[tid] + gate_dot8(WB0, tid, xs, 24);
        __syncthreads();
        if (tid < 64) {
            float ig = sigf(gates[tid]);
            float fg = sigf(gates[64 + tid]);
            float gg = tanhf(gates[128 + tid]);
            float og = sigf(gates[192 + tid]);
            float cv = fg * cs[0][tid] + ig * gg;
            cs[0][tid] = cv;
            hs[0][tid] = og * tanhf(cv);
        }
        __syncthreads();
        // ---- layer 1 (K = 64 + 64) ----
        if (tid < 64) xs[tid] = hs[0][tid];
        else if (tid < 128) xs[tid] = hs[1][tid - 64];
        __syncthreads();
        gates[tid] = lb1[tid] + gate_dot8(WB1, tid, xs, 16);
        __syncthreads();
        if (tid < 64) {
            float ig = sigf(gates[tid]);
            float fg = sigf(gates[64 + tid]);
            float gg = tanhf(gates[128 + tid]);
            float og = sigf(gates[192 + tid]);
            float cv = fg * cs[1][tid] + ig * gg;
            cs[1][tid] = cv;
            hs[1][tid] = og * tanhf(cv);
        }
        __syncthreads();
        // ---- layer 2 (K = 64 + 64) ----
        if (tid < 64) xs[tid] = hs[1][tid];
        else if (tid < 128) xs[tid] = hs[2][tid - 64];
        __syncthreads();
        gates[tid] = lb2[tid] + gate_dot8(WB2, tid, xs, 16);
        __syncthreads();
        if (tid < 64) {
            float ig = sigf(gates[tid]);
            float fg = sigf(gates[64 + tid]);
            float gg = tanhf(gates[128 + tid]);
            float og = sigf(gates[192 + tid]);
            float cv = fg * cs[2][tid] + ig * gg;
            cs[2][tid] = cv;
            hs[2][tid] = og * tanhf(cv);
        }
        __syncthreads();
        // ---- attention over this graph's 25 nodes; q = hs[2] ----
        float ev = -1e30f;
        if (tid < 25) {
            float acc = 0.f;
            for (int d = 0; d < 64; ++d)
                acc = fmaf(hl[tid * 65 + d], hs[2][d], acc);
            ev = acc;
        }
        if (tid < 64) {
            float mx = ev;
            #pragma unroll
            for (int off = 16; off; off >>= 1) mx = fmaxf(mx, __shfl_xor(mx, off, 32));
            float ex = (tid < 25) ? expf(ev - mx) : 0.f;
            float sm = ex;
            #pragma unroll
            for (int off = 16; off; off >>= 1) sm += __shfl_xor(sm, off, 32);
            if (tid < 25) als[tid] = ex / sm;
        }
        __syncthreads();
        if (tid < 64) {
            float rdt = 0.f;
            #pragma unroll
            for (int n = 0; n < 25; ++n) rdt = fmaf(als[n], hl[n * 65 + tid], rdt);
            qstar[tid]      = hs[2][tid];
            qstar[64 + tid] = rdt;
        }
        __syncthreads();
    }

    if (tid < 64) {
        float acc = pb[tid];
        #pragma unroll 8
        for (int k = 0; k < 128; ++k)
            acc = fmaf(qstar[k], pW[(size_t)k * 64 + tid], acc);
        float part = fmaxf(acc, 0.f) * fW[tid];
        #pragma unroll
        for (int off = 32; off; off >>= 1) part += __shfl_xor(part, off, 64);
        if (tid == 0) out[g] = 1.f / (1.f + expf(-(part + fb[0])));
    }
}

// ---------------------------------------------------------------------------
extern "C" void kernel_launch(void* const* d_in, const int* in_sizes, int n_in,
                              void* d_out, int out_size, void* d_ws, size_t ws_size,
                              hipStream_t stream)
{
    const float* n_feats = (const float*)d_in[0];
    const float* e_feats = (const float*)d_in[1];
    const int*   src     = (const int*)d_in[2];
    const int*   dst     = (const int*)d_in[3];
    const float* proj_W  = (const float*)d_in[5];
    const float* proj_b  = (const float*)d_in[6];
    const float* eW1     = (const float*)d_in[7];
    const float* eb1     = (const float*)d_in[8];
    const float* eW2     = (const float*)d_in[9];
    const float* eb2     = (const float*)d_in[10];
    const float* conv_b  = (const float*)d_in[11];
    const float* gWi     = (const float*)d_in[12];
    const float* gWh     = (const float*)d_in[13];
    const float* gbi     = (const float*)d_in[14];
    const float* gbh     = (const float*)d_in[15];
    const float* lWi0    = (const float*)d_in[16];
    const float* lWh0    = (const float*)d_in[17];
    const float* lb0     = (const float*)d_in[18];
    const float* lWi1    = (const float*)d_in[19];
    const float* lWh1    = (const float*)d_in[20];
    const float* lb1     = (const float*)d_in[21];
    const float* lWi2    = (const float*)d_in[22];
    const float* lWh2    = (const float*)d_in[23];
    const float* lb2     = (const float*)d_in[24];
    const float* pW      = (const float*)d_in[25];
    const float* pb      = (const float*)d_in[26];
    const float* fW      = (const float*)d_in[27];
    const float* fb      = (const float*)d_in[28];

    const int N = in_sizes[0] / 74;   // 25000
    const int E = in_sizes[1] / 12;   // 50000
    const int G = out_size;           // 1000

    float* ws   = (float*)d_ws;
    float* h    = ws;                                        // N*64 f32
    float* msum = h + (size_t)N * 64;                        // N*64 f32
    _Float16* h16 = (_Float16*)(msum + (size_t)N * 64);     // N*64 f16
    _Float16* t16 = h16 + (size_t)N * 64;                   // E*64 f16
    unsigned short* w_staged = (unsigned short*)(t16 + (size_t)E * 64); // 65*4096 shorts
    _Float16* WiT = (_Float16*)(w_staged + 65 * 4096);      // 192*64 f16
    _Float16* WhT = WiT + 12288;                            // 192*64 f16
    _Float16* WB0 = WhT + 12288;                            // 192*256 f16
    _Float16* WB1 = WB0 + 49152;                            // 128*256 f16
    _Float16* WB2 = WB1 + 32768;                            // 128*256 f16

    // one-time weight prep
    prep_w_kernel<<<130, 256, 0, stream>>>(eW2, eb2, w_staged);
    prep_gruw_kernel<<<96, 256, 0, stream>>>(gWi, gWh, WiT, WhT);
    prep_s2sw_kernel<<<448, 256, 0, stream>>>(lWi0, lWh0, lWi1, lWh1, lWi2, lWh2,
                                              WB0, WB1, WB2);

    // node projection (h f32 + f16) and edge-net first layer (f16)
    rowmat_relu_t<74, 0><<<(N + 31) / 32, 256, 0, stream>>>(n_feats, proj_W, proj_b, h, h16, N);
    rowmat_relu_t<12, 1><<<(E + 31) / 32, 256, 0, stream>>>(e_feats, eW1, eb1, nullptr, t16, E);

    // 3 rounds of message passing + GRU
    for (int it = 0; it < 3; ++it) {
        hipMemsetAsync(msum, 0, (size_t)N * 64 * sizeof(float), stream);
        msg_mfma_kernel<<<(E + 63) / 64, 256, 0, stream>>>(t16, h16, src, dst, w_staged, msum, E);
        gru_mfma_kernel<<<(N + 63) / 64, 256, 0, stream>>>(msum, h, h16, WiT, WhT,
                                                           gbi, gbh, conv_b, N);
    }

    // fused Set2Set (3 iters) + predict head: 1 graph per block
    set2set_kernel<<<G, 256, 0, stream>>>(h, WB0, WB1, WB2, lb0, lb1, lb2,
                                          pW, pb, fW, fb, (float*)d_out);
}

// Round 13
// 268.324 us; speedup vs baseline: 1.0695x; 1.0456x over previous
//
#include <hip/hip_runtime.h>
#include <math.h>

__device__ __forceinline__ float sigf(float x) { return 1.f / (1.f + expf(-x)); }

using half8v = __attribute__((ext_vector_type(8))) _Float16;
using f32x4  = __attribute__((ext_vector_type(4))) float;

__device__ __forceinline__ unsigned short f2h(float x) {
    union { _Float16 h; unsigned short u; } c; c.h = (_Float16)x; return c.u;
}
__device__ __forceinline__ half8v u2h(uint4 v) {
    union { uint4 u; half8v h; } c; c.u = v; return c.h;
}

// ---------------------------------------------------------------------------
// Templated row-matmul+ReLU (round-9 validated: unroll-2, launch_bounds(,4)).
// ---------------------------------------------------------------------------
template<int K, int MODE>
__global__ __launch_bounds__(256, 4)
void rowmat_relu_t(const float* __restrict__ in, const float* __restrict__ W,
                   const float* __restrict__ b, float* __restrict__ out32,
                   _Float16* __restrict__ out16, int R)
{
    __shared__ float Wl[K * 64];
    __shared__ float rowsS[32 * K];

    const int tid  = threadIdx.x;
    const int row0 = blockIdx.x * 32;

    for (int i = tid; i < K * 64; i += 256)
        Wl[i] = W[i];
    const int lim = (R - row0 >= 32 ? 32 : (R - row0)) * K;
    for (int i = tid; i < 32 * K; i += 256)
        rowsS[i] = (i < lim) ? in[(size_t)row0 * K + i] : 0.f;
    __syncthreads();

    const int wave = tid >> 6, lane = tid & 63;
    const float bv = b[lane];

    float acc[8];
    #pragma unroll
    for (int rr = 0; rr < 8; ++rr) acc[rr] = bv;

    #pragma unroll 2
    for (int k = 0; k < K; ++k) {
        const float wv = Wl[k * 64 + lane];
        #pragma unroll
        for (int rr = 0; rr < 8; ++rr)
            acc[rr] = fmaf(rowsS[(wave * 8 + rr) * K + k], wv, acc[rr]);
    }

    #pragma unroll
    for (int rr = 0; rr < 8; ++rr) {
        const int row = row0 + wave * 8 + rr;
        if (row < R) {
            const float v = fmaxf(acc[rr], 0.f);
            if (MODE == 0) out32[(size_t)row * 64 + lane] = v;
            out16[(size_t)row * 64 + lane] = (_Float16)v;
        }
    }
}

// ---------------------------------------------------------------------------
// One-time edge-net weight prep v2: COALESCED per-wave fragment layout.
// 16B slot (chunk kc, wn, tn, ks, lane) at uint4 index kc*512 + sub*64 + lane,
// sub = (wn*2+tn)*2+ks, lane = kg*16+l15. Content (validated fragment):
//   M[kc*64 + (kg+ks*4)*8 + m][o],  m=0..7,  o = wn*32 + tn*16 + l15
// where M[j][o] = eW2[j*64+o] (j<4096) else eb2[(j-4096)*64+o] (bias chunk).
// A wave's 64 lanes read ONE contiguous 1KB line per fragment -> fully
// coalesced L2 reads, no LDS staging needed in msg.
// ---------------------------------------------------------------------------
__global__ __launch_bounds__(256)
void prep_w_kernel(const float* __restrict__ eW2, const float* __restrict__ eb2,
                   unsigned short* __restrict__ w_staged)
{
    int slot = blockIdx.x * 256 + threadIdx.x;     // 65*512 slots
    if (slot >= 65 * 512) return;
    int kc   = slot >> 9;
    int s    = slot & 511;
    int sub  = s >> 6, lane = s & 63;
    int wn   = sub >> 2, tn = (sub >> 1) & 1, ks = sub & 1;
    int kg   = lane >> 4, l15 = lane & 15;
    int o    = wn * 32 + tn * 16 + l15;
    int seg  = kg + ks * 4;
    int j0   = kc * 64 + seg * 8;
    unsigned int packed[4];
    #pragma unroll
    for (int p = 0; p < 4; ++p) {
        int j = j0 + p * 2;
        float v0 = (j     < 4096) ? eW2[(size_t)j * 64 + o]       : eb2[(size_t)(j - 4096) * 64 + o];
        float v1 = (j + 1 < 4096) ? eW2[(size_t)(j + 1) * 64 + o] : eb2[(size_t)(j + 1 - 4096) * 64 + o];
        packed[p] = (unsigned int)f2h(v0) | ((unsigned int)f2h(v1) << 16);
    }
    uint4 st = {packed[0], packed[1], packed[2], packed[3]};
    ((uint4*)w_staged)[slot] = st;
}

// ---------------------------------------------------------------------------
// One-time GRU weight prep: WiT/WhT[n][k] = (f16) W[k*192+n].
// ---------------------------------------------------------------------------
__global__ __launch_bounds__(256)
void prep_gruw_kernel(const float* __restrict__ Wi, const float* __restrict__ Wh,
                      _Float16* __restrict__ WiT, _Float16* __restrict__ WhT)
{
    int idx = blockIdx.x * 256 + threadIdx.x;
    if (idx >= 2 * 12288) return;
    const float* W = (idx < 12288) ? Wi : Wh;
    _Float16*    O = (idx < 12288) ? WiT : WhT;
    int r = idx & 12287;
    int n = r >> 6, k = r & 63;
    O[n * 64 + k] = (_Float16)W[(size_t)k * 192 + n];
}

// ---------------------------------------------------------------------------
// One-time Set2Set LSTM weight prep: k-block row-major f16 (coalesced).
// ---------------------------------------------------------------------------
__global__ __launch_bounds__(256)
void prep_s2sw_kernel(const float* __restrict__ lWi0, const float* __restrict__ lWh0,
                      const float* __restrict__ lWi1, const float* __restrict__ lWh1,
                      const float* __restrict__ lWi2, const float* __restrict__ lWh2,
                      _Float16* __restrict__ WB0, _Float16* __restrict__ WB1,
                      _Float16* __restrict__ WB2)
{
    int idx = blockIdx.x * 256 + threadIdx.x;   // 114688 total
    if (idx < 49152) {
        int k = idx >> 8, n = idx & 255;
        float v = (k < 128) ? lWi0[(size_t)k * 256 + n] : lWh0[(size_t)(k - 128) * 256 + n];
        WB0[((k >> 3) * 2048) + n * 8 + (k & 7)] = (_Float16)v;
    } else if (idx < 81920) {
        int r = idx - 49152;
        int k = r >> 8, n = r & 255;
        float v = (k < 64) ? lWi1[(size_t)k * 256 + n] : lWh1[(size_t)(k - 64) * 256 + n];
        WB1[((k >> 3) * 2048) + n * 8 + (k & 7)] = (_Float16)v;
    } else if (idx < 114688) {
        int r = idx - 81920;
        int k = r >> 8, n = r & 255;
        float v = (k < 64) ? lWi2[(size_t)k * 256 + n] : lWh2[(size_t)(k - 64) * 256 + n];
        WB2[((k >> 3) * 2048) + n * 8 + (k & 7)] = (_Float16)v;
    }
}

// ---------------------------------------------------------------------------
// MFMA NNConv message v3: NO B-LDS, NO main-loop barriers.
// Rounds 9-12 all flat ~53-57us: per-chunk LDS round-trip (global->reg->LDS->
// reg) + barrier phase-locking consumed ~1000+ cyc/chunk of LDS pipe. B is
// L2-resident (532KB, read by every block) -> read fragments DIRECTLY from
// the coalesced w_staged v2 layout (1KB contiguous per wave-instruction).
// Depth-4 in-place register rotation (static names, 16 loads in flight).
// A-frags/epilogue identical to validated round-11 kernel.
// ---------------------------------------------------------------------------
__global__ __launch_bounds__(256, 3)
void msg_mfma_kernel(const _Float16* __restrict__ t16, const _Float16* __restrict__ h16,
                     const int* __restrict__ src, const int* __restrict__ dst,
                     const unsigned short* __restrict__ w_staged,
                     float* __restrict__ msum, int E)
{
    __shared__ _Float16 tS[64 * 70];     // [k][e+pad] — only LDS left

    const int tid  = threadIdx.x;
    const int lane = tid & 63;
    const int wave = tid >> 6;
    const int wm   = wave & 1, wn = wave >> 1;
    const int e0   = blockIdx.x * 64;

    // stage t tile transposed into tS[k][e] (f16) — unchanged
    #pragma unroll
    for (int p = 0; p < 2; ++p) {
        int slot = tid + p * 256;               // 0..511
        int e = slot >> 3, k0 = (slot & 7) * 8;
        int ee = e0 + e;
        half8v tv8 = (half8v)(_Float16)0.f;
        if (ee < E) tv8 = ((const half8v*)(t16 + (size_t)ee * 64))[slot & 7];
        #pragma unroll
        for (int j = 0; j < 8; ++j)
            tS[(k0 + j) * 70 + e] = tv8[j];
    }

    const int l15 = lane & 15;
    const int kg  = lane >> 4;          // 0..3

    // resident h16 A-fragments (gru-validated 16x16x32 A layout)
    half8v Hh[2][2];
    #pragma unroll
    for (int tm = 0; tm < 2; ++tm) {
        const int edge = e0 + wm * 32 + tm * 16 + l15;
        const int sidx = (edge < E) ? src[edge] : 0;
        const half8v* hp = (const half8v*)(h16 + (size_t)sidx * 64);
        Hh[tm][0] = hp[kg];
        Hh[tm][1] = hp[kg + 4];
    }

    const uint4* W4  = (const uint4*)w_staged;
    const int    wb  = wn * 256 + lane;   // fragment base within chunk

    // 4 rotation slots x 4 fragments (tn0ks0, tn0ks1, tn1ks0, tn1ks1)
    uint4 S0a, S0b, S0c, S0d, S1a, S1b, S1c, S1d;
    uint4 S2a, S2b, S2c, S2d, S3a, S3b, S3c, S3d;

#define LOADC(A, B, C, D, cc)                                         \
    { size_t off = (size_t)(cc) * 512 + wb;                           \
      A = W4[off]; B = W4[off + 64]; C = W4[off + 128]; D = W4[off + 192]; }

#define COMP(A, B, C, D, TV0, TV1)                                            \
    { half8v af00 = Hh[0][0] * (TV0), af01 = Hh[0][1] * (TV0);                \
      half8v af10 = Hh[1][0] * (TV1), af11 = Hh[1][1] * (TV1);                \
      half8v b00 = u2h(A), b01 = u2h(B), b10 = u2h(C), b11 = u2h(D);          \
      acc00 = __builtin_amdgcn_mfma_f32_16x16x32_f16(af00, b00, acc00, 0,0,0);\
      acc01 = __builtin_amdgcn_mfma_f32_16x16x32_f16(af00, b10, acc01, 0,0,0);\
      acc10 = __builtin_amdgcn_mfma_f32_16x16x32_f16(af10, b00, acc10, 0,0,0);\
      acc11 = __builtin_amdgcn_mfma_f32_16x16x32_f16(af10, b10, acc11, 0,0,0);\
      acc00 = __builtin_amdgcn_mfma_f32_16x16x32_f16(af01, b01, acc00, 0,0,0);\
      acc01 = __builtin_amdgcn_mfma_f32_16x16x32_f16(af01, b11, acc01, 0,0,0);\
      acc10 = __builtin_amdgcn_mfma_f32_16x16x32_f16(af11, b01, acc10, 0,0,0);\
      acc11 = __builtin_amdgcn_mfma_f32_16x16x32_f16(af11, b11, acc11, 0,0,0); }

    LOADC(S0a, S0b, S0c, S0d, 0)
    LOADC(S1a, S1b, S1c, S1d, 1)
    LOADC(S2a, S2b, S2c, S2d, 2)
    LOADC(S3a, S3b, S3c, S3d, 3)

    f32x4 acc00, acc01, acc10, acc11;
    #pragma unroll
    for (int j = 0; j < 4; ++j) { acc00[j] = 0.f; acc01[j] = 0.f; acc10[j] = 0.f; acc11[j] = 0.f; }

    __syncthreads();   // tS visible (one-time)

    const int tvb0 = wm * 32 + l15, tvb1 = wm * 32 + 16 + l15;

    for (int c = 0; c < 64; c += 4) {
        // tv for chunks c..c+3 (issue together; LDS latency overlaps)
        _Float16 ta0 = tS[(c + 0) * 70 + tvb0], tb0 = tS[(c + 0) * 70 + tvb1];
        _Float16 ta1 = tS[(c + 1) * 70 + tvb0], tb1 = tS[(c + 1) * 70 + tvb1];
        _Float16 ta2 = tS[(c + 2) * 70 + tvb0], tb2 = tS[(c + 2) * 70 + tvb1];
        _Float16 ta3 = tS[(c + 3) * 70 + tvb0], tb3 = tS[(c + 3) * 70 + tvb1];

        COMP(S0a, S0b, S0c, S0d, ta0, tb0)
        if (c + 4 <= 64) LOADC(S0a, S0b, S0c, S0d, c + 4)
        COMP(S1a, S1b, S1c, S1d, ta1, tb1)
        if (c + 5 <= 64) LOADC(S1a, S1b, S1c, S1d, c + 5)
        COMP(S2a, S2b, S2c, S2d, ta2, tb2)
        if (c + 6 <= 64) LOADC(S2a, S2b, S2c, S2d, c + 6)
        COMP(S3a, S3b, S3c, S3d, ta3, tb3)
        if (c + 7 <= 64) LOADC(S3a, S3b, S3c, S3d, c + 7)
    }
    // bias chunk 64 (t == 1), resident in slot 0 (loaded at c=60)
    {
        const _Float16 one = (_Float16)1.0f;
        COMP(S0a, S0b, S0c, S0d, one, one)
    }
#undef LOADC
#undef COMP

    // epilogue: 16x16 C layout (gru-validated): col=l15, row=kg*4+j
    f32x4 acc[2][2] = {{acc00, acc01}, {acc10, acc11}};
    #pragma unroll
    for (int tm = 0; tm < 2; ++tm) {
        #pragma unroll
        for (int j = 0; j < 4; ++j) {
            const int edge = e0 + wm * 32 + tm * 16 + kg * 4 + j;
            if (edge >= E) continue;
            const int d = dst[edge];
            #pragma unroll
            for (int tn = 0; tn < 2; ++tn)
                atomicAdd(&msum[(size_t)d * 64 + wn * 32 + tn * 16 + l15], acc[tm][tn][j]);
        }
    }
}

// ---------------------------------------------------------------------------
// MFMA GRU — round-4 known-good version (weights LDS-staged per block).
// ---------------------------------------------------------------------------
__global__ __launch_bounds__(256, 2)
void gru_mfma_kernel(const float* __restrict__ msum, float* __restrict__ h,
                     _Float16* __restrict__ h16,
                     const _Float16* __restrict__ WiT, const _Float16* __restrict__ WhT,
                     const float* __restrict__ bi, const float* __restrict__ bh,
                     const float* __restrict__ conv_b, int N)
{
    __shared__ _Float16 BtI[192 * 72];   // [n][k+pad]
    __shared__ _Float16 BtH[192 * 72];
    __shared__ _Float16 Am[64 * 72];     // [row][k+pad]
    __shared__ _Float16 Ah[64 * 72];

    const int tid  = threadIdx.x;
    const int lane = tid & 63;
    const int wave = tid >> 6;
    const int m0   = wave * 16;
    const int row0 = blockIdx.x * 64;

    #pragma unroll
    for (int p = 0; p < 6; ++p) {
        int slot = tid + p * 256;            // 0..1535
        int n = slot >> 3, k0 = (slot & 7) * 8;
        uint4 vi = ((const uint4*)WiT)[slot];
        uint4 vh = ((const uint4*)WhT)[slot];
        *(uint4*)&BtI[n * 72 + k0] = vi;
        *(uint4*)&BtH[n * 72 + k0] = vh;
    }
    #pragma unroll
    for (int p = 0; p < 4; ++p) {
        int idx = tid + p * 256;             // 0..1023
        int r = idx >> 4, k4 = (idx & 15) * 4;
        int row = row0 + r;
        float4 mv = make_float4(0.f, 0.f, 0.f, 0.f);
        if (row < N) mv = *(const float4*)&msum[(size_t)row * 64 + k4];
        float4 cb = *(const float4*)&conv_b[k4];
        union { _Float16 hx[4]; uint2 u2; } pk;
        pk.hx[0] = (_Float16)fmaxf(mv.x + cb.x, 0.f);
        pk.hx[1] = (_Float16)fmaxf(mv.y + cb.y, 0.f);
        pk.hx[2] = (_Float16)fmaxf(mv.z + cb.z, 0.f);
        pk.hx[3] = (_Float16)fmaxf(mv.w + cb.w, 0.f);
        *(uint2*)&Am[r * 72 + k4] = pk.u2;
    }
    #pragma unroll
    for (int p = 0; p < 2; ++p) {
        int idx = tid + p * 256;             // 0..511
        int r = idx >> 3, k0 = (idx & 7) * 8;
        int row = row0 + r;
        uint4 v = {0u, 0u, 0u, 0u};
        if (row < N) v = *(const uint4*)&h16[(size_t)row * 64 + k0];
        *(uint4*)&Ah[r * 72 + k0] = v;
    }
    __syncthreads();

    const int l15 = lane & 15;

    f32x4 acc_i[12], acc_h[12];
    #pragma unroll
    for (int nt = 0; nt < 12; ++nt) {
        #pragma unroll
        for (int j = 0; j < 4; ++j) { acc_i[nt][j] = 0.f; acc_h[nt][j] = 0.f; }
    }

    #pragma unroll
    for (int ks = 0; ks < 2; ++ks) {
        const int ka = ks * 32 + (lane >> 4) * 8;
        half8v am = *(const half8v*)&Am[(m0 + l15) * 72 + ka];
        half8v ah = *(const half8v*)&Ah[(m0 + l15) * 72 + ka];
        #pragma unroll
        for (int nt = 0; nt < 12; ++nt) {
            half8v b_i = *(const half8v*)&BtI[(nt * 16 + l15) * 72 + ka];
            half8v b_h = *(const half8v*)&BtH[(nt * 16 + l15) * 72 + ka];
            acc_i[nt] = __builtin_amdgcn_mfma_f32_16x16x32_f16(am, b_i, acc_i[nt], 0, 0, 0);
            acc_h[nt] = __builtin_amdgcn_mfma_f32_16x16x32_f16(ah, b_h, acc_h[nt], 0, 0, 0);
        }
    }

    const int rgrp = lane >> 4;
    #pragma unroll
    for (int nt0 = 0; nt0 < 4; ++nt0) {
        const int c = nt0 * 16 + l15;
        const float bir = bi[c],        bhr = bh[c];
        const float biz = bi[64 + c],   bhz = bh[64 + c];
        const float bin = bi[128 + c],  bhn = bh[128 + c];
        #pragma unroll
        for (int j = 0; j < 4; ++j) {
            const int row = row0 + m0 + rgrp * 4 + j;
            if (row >= N) continue;
            float rg = sigf(acc_i[nt0][j]      + bir + acc_h[nt0][j]      + bhr);
            float zg = sigf(acc_i[4 + nt0][j]  + biz + acc_h[4 + nt0][j]  + bhz);
            float ng = tanhf(acc_i[8 + nt0][j] + bin + rg * (acc_h[8 + nt0][j] + bhn));
            float hold = h[(size_t)row * 64 + c];
            float hv = (1.f - zg) * ng + zg * hold;
            h[(size_t)row * 64 + c]   = hv;
            h16[(size_t)row * 64 + c] = (_Float16)hv;
        }
    }
}

// ---------------------------------------------------------------------------
// Per-thread gate dot: k-block row-major f16 weights (coalesced half8v).
// ---------------------------------------------------------------------------
__device__ __forceinline__ float gate_dot8(const _Float16* __restrict__ WB,
                                           int tid, const float* __restrict__ xs,
                                           int nblk)
{
    float a0 = 0.f, a1 = 0.f, a2 = 0.f, a3 = 0.f;
    #pragma unroll 4
    for (int b = 0; b < nblk; ++b) {
        half8v w = *(const half8v*)(WB + (size_t)b * 2048 + tid * 8);
        float4 xa = *(const float4*)&xs[b * 8];
        float4 xb = *(const float4*)&xs[b * 8 + 4];
        a0 = fmaf((float)w[0], xa.x, a0);
        a1 = fmaf((float)w[1], xa.y, a1);
        a2 = fmaf((float)w[2], xa.z, a2);
        a3 = fmaf((float)w[3], xa.w, a3);
        a0 = fmaf((float)w[4], xb.x, a0);
        a1 = fmaf((float)w[5], xb.y, a1);
        a2 = fmaf((float)w[6], xb.z, a2);
        a3 = fmaf((float)w[7], xb.w, a3);
    }
    return (a0 + a1) + (a2 + a3);
}

// ---------------------------------------------------------------------------
// Fused Set2Set + head: 1 graph per block, f16 k-block weights, f32 state.
// ---------------------------------------------------------------------------
__global__ __launch_bounds__(256)
void set2set_kernel(const float* __restrict__ h,
                    const _Float16* __restrict__ WB0, const _Float16* __restrict__ WB1,
                    const _Float16* __restrict__ WB2,
                    const float* __restrict__ lb0, const float* __restrict__ lb1,
                    const float* __restrict__ lb2,
                    const float* __restrict__ pW, const float* __restrict__ pb,
                    const float* __restrict__ fW, const float* __restrict__ fb,
                    float* __restrict__ out)
{
    const int g   = blockIdx.x;
    const int tid = threadIdx.x;

    __shared__ float hl[25 * 65];
    __shared__ float hs[3][64], cs[3][64];
    __shared__ float qstar[128];
    __shared__ __align__(16) float xs[192];
    __shared__ float gates[256];
    __shared__ float als[32];

    for (int idx = tid; idx < 25 * 64; idx += 256) {
        int n = idx >> 6, d = idx & 63;
        hl[n * 65 + d] = h[((size_t)g * 25 + n) * 64 + d];
    }
    if (tid < 128) qstar[tid] = 0.f;
    if (tid < 64) {
        #pragma unroll
        for (int l = 0; l < 3; ++l) { hs[l][tid] = 0.f; cs[l][tid] = 0.f; }
    }
    __syncthreads();

    for (int it = 0; it < 3; ++it) {
        // ---- layer 0 (K = 128 + 64) ----
        if (tid < 128) xs[tid] = qstar[tid];
        else if (tid < 192) xs[tid] = hs[0][tid - 128];
        __syncthreads();
        gates[tid] = lb0[tid] + gate_dot8(WB0, tid, xs, 24);
        __syncthreads();
        if (tid < 64) {
            float ig = sigf(gates[tid]);
            float fg = sigf(gates[64 + tid]);
            float gg = tanhf(gates[128 + tid]);
            float og = sigf(gates[192 + tid]);
            float cv = fg * cs[0][tid] + ig * gg;
            cs[0][tid] = cv;
            hs[0][tid] = og * tanhf(cv);
        }
        __syncthreads();
        // ---- layer 1 (K = 64 + 64) ----
        if (tid < 64) xs[tid] = hs[0][tid];
        else if (tid < 128) xs[tid] = hs[1][tid - 64];
        __syncthreads();
        gates[tid] = lb1[tid] + gate_dot8(WB1, tid, xs, 16);
        __syncthreads();
        if (tid < 64) {
            float ig = sigf(gates[tid]);
            float fg = sigf(gates[64 + tid]);
            float gg = tanhf(gates[128 + tid]);
            float og = sigf(gates[192 + tid]);
            float cv = fg * cs[1][tid] + ig * gg;
            cs[1][tid] = cv;
            hs[1][tid] = og * tanhf(cv);
        }
        __syncthreads();
        // ---- layer 2 (K = 64 + 64) ----
        if (tid < 64) xs[tid] = hs[1][tid];
        else if (tid < 128) xs[tid] = hs[2][tid - 64];
        __syncthreads();
        gates[tid] = lb2[tid] + gate_dot8(WB2, tid, xs, 16);
        __syncthreads();
        if (tid < 64) {
            float ig = sigf(gates[tid]);
            float fg = sigf(gates[64 + tid]);
            float gg = tanhf(gates[128 + tid]);
            float og = sigf(gates[192 + tid]);
            float cv = fg * cs[2][tid] + ig * gg;
            cs[2][tid] = cv;
            hs[2][tid] = og * tanhf(cv);
        }
        __syncthreads();
        // ---- attention over this graph's 25 nodes; q = hs[2] ----
        float ev = -1e30f;
        if (tid < 25) {
            float acc = 0.f;
            for (int d = 0; d < 64; ++d)
                acc = fmaf(hl[tid * 65 + d], hs[2][d], acc);
            ev = acc;
        }
        if (tid < 64) {
            float mx = ev;
            #pragma unroll
            for (int off = 16; off; off >>= 1) mx = fmaxf(mx, __shfl_xor(mx, off, 32));
            float ex = (tid < 25) ? expf(ev - mx) : 0.f;
            float sm = ex;
            #pragma unroll
            for (int off = 16; off; off >>= 1) sm += __shfl_xor(sm, off, 32);
            if (tid < 25) als[tid] = ex / sm;
        }
        __syncthreads();
        if (tid < 64) {
            float rdt = 0.f;
            #pragma unroll
            for (int n = 0; n < 25; ++n) rdt = fmaf(als[n], hl[n * 65 + tid], rdt);
            qstar[tid]      = hs[2][tid];
            qstar[64 + tid] = rdt;
        }
        __syncthreads();
    }

    if (tid < 64) {
        float acc = pb[tid];
        #pragma unroll 8
        for (int k = 0; k < 128; ++k)
            acc = fmaf(qstar[k], pW[(size_t)k * 64 + tid], acc);
        float part = fmaxf(acc, 0.f) * fW[tid];
        #pragma unroll
        for (int off = 32; off; off >>= 1) part += __shfl_xor(part, off, 64);
        if (tid == 0) out[g] = 1.f / (1.f + expf(-(part + fb[0])));
    }
}

// ---------------------------------------------------------------------------
extern "C" void kernel_launch(void* const* d_in, const int* in_sizes, int n_in,
                              void* d_out, int out_size, void* d_ws, size_t ws_size,
                              hipStream_t stream)
{
    const float* n_feats = (const float*)d_in[0];
    const float* e_feats = (const float*)d_in[1];
    const int*   src     = (const int*)d_in[2];
    const int*   dst     = (const int*)d_in[3];
    const float* proj_W  = (const float*)d_in[5];
    const float* proj_b  = (const float*)d_in[6];
    const float* eW1     = (const float*)d_in[7];
    const float* eb1     = (const float*)d_in[8];
    const float* eW2     = (const float*)d_in[9];
    const float* eb2     = (const float*)d_in[10];
    const float* conv_b  = (const float*)d_in[11];
    const float* gWi     = (const float*)d_in[12];
    const float* gWh     = (const float*)d_in[13];
    const float* gbi     = (const float*)d_in[14];
    const float* gbh     = (const float*)d_in[15];
    const float* lWi0    = (const float*)d_in[16];
    const float* lWh0    = (const float*)d_in[17];
    const float* lb0     = (const float*)d_in[18];
    const float* lWi1    = (const float*)d_in[19];
    const float* lWh1    = (const float*)d_in[20];
    const float* lb1     = (const float*)d_in[21];
    const float* lWi2    = (const float*)d_in[22];
    const float* lWh2    = (const float*)d_in[23];
    const float* lb2     = (const float*)d_in[24];
    const float* pW      = (const float*)d_in[25];
    const float* pb      = (const float*)d_in[26];
    const float* fW      = (const float*)d_in[27];
    const float* fb      = (const float*)d_in[28];

    const int N = in_sizes[0] / 74;   // 25000
    const int E = in_sizes[1] / 12;   // 50000
    const int G = out_size;           // 1000

    float* ws   = (float*)d_ws;
    float* h    = ws;                                        // N*64 f32
    float* msum = h + (size_t)N * 64;                        // N*64 f32
    _Float16* h16 = (_Float16*)(msum + (size_t)N * 64);     // N*64 f16
    _Float16* t16 = h16 + (size_t)N * 64;                   // E*64 f16
    unsigned short* w_staged = (unsigned short*)(t16 + (size_t)E * 64); // 65*4096 shorts
    _Float16* WiT = (_Float16*)(w_staged + 65 * 4096);      // 192*64 f16
    _Float16* WhT = WiT + 12288;                            // 192*64 f16
    _Float16* WB0 = WhT + 12288;                            // 192*256 f16
    _Float16* WB1 = WB0 + 49152;                            // 128*256 f16
    _Float16* WB2 = WB1 + 32768;                            // 128*256 f16

    // one-time weight prep
    prep_w_kernel<<<130, 256, 0, stream>>>(eW2, eb2, w_staged);
    prep_gruw_kernel<<<96, 256, 0, stream>>>(gWi, gWh, WiT, WhT);
    prep_s2sw_kernel<<<448, 256, 0, stream>>>(lWi0, lWh0, lWi1, lWh1, lWi2, lWh2,
                                              WB0, WB1, WB2);

    // node projection (h f32 + f16) and edge-net first layer (f16)
    rowmat_relu_t<74, 0><<<(N + 31) / 32, 256, 0, stream>>>(n_feats, proj_W, proj_b, h, h16, N);
    rowmat_relu_t<12, 1><<<(E + 31) / 32, 256, 0, stream>>>(e_feats, eW1, eb1, nullptr, t16, E);

    // 3 rounds of message passing + GRU
    for (int it = 0; it < 3; ++it) {
        hipMemsetAsync(msum, 0, (size_t)N * 64 * sizeof(float), stream);
        msg_mfma_kernel<<<(E + 63) / 64, 256, 0, stream>>>(t16, h16, src, dst, w_staged, msum, E);
        gru_mfma_kernel<<<(N + 63) / 64, 256, 0, stream>>>(msum, h, h16, WiT, WhT,
                                                           gbi, gbh, conv_b, N);
    }

    // fused Set2Set (3 iters) + predict head: 1 graph per block
    set2set_kernel<<<G, 256, 0, stream>>>(h, WB0, WB1, WB2, lb0, lb1, lb2,
                                          pW, pb, fW, fb, (float*)d_out);
}

// Round 14
// 267.907 us; speedup vs baseline: 1.0712x; 1.0016x over previous
//
#include <hip/hip_runtime.h>
#include <math.h>

__device__ __forceinline__ float sigf(float x) { return 1.f / (1.f + expf(-x)); }

using half8v = __attribute__((ext_vector_type(8))) _Float16;
using f32x4  = __attribute__((ext_vector_type(4))) float;

__device__ __forceinline__ unsigned short f2h(float x) {
    union { _Float16 h; unsigned short u; } c; c.h = (_Float16)x; return c.u;
}
__device__ __forceinline__ half8v u2h(uint4 v) {
    union { uint4 u; half8v h; } c; c.u = v; return c.h;
}

// ---------------------------------------------------------------------------
// Templated row-matmul+ReLU (round-9 validated: unroll-2, launch_bounds(,4)).
// ---------------------------------------------------------------------------
template<int K, int MODE>
__global__ __launch_bounds__(256, 4)
void rowmat_relu_t(const float* __restrict__ in, const float* __restrict__ W,
                   const float* __restrict__ b, float* __restrict__ out32,
                   _Float16* __restrict__ out16, int R)
{
    __shared__ float Wl[K * 64];
    __shared__ float rowsS[32 * K];

    const int tid  = threadIdx.x;
    const int row0 = blockIdx.x * 32;

    for (int i = tid; i < K * 64; i += 256)
        Wl[i] = W[i];
    const int lim = (R - row0 >= 32 ? 32 : (R - row0)) * K;
    for (int i = tid; i < 32 * K; i += 256)
        rowsS[i] = (i < lim) ? in[(size_t)row0 * K + i] : 0.f;
    __syncthreads();

    const int wave = tid >> 6, lane = tid & 63;
    const float bv = b[lane];

    float acc[8];
    #pragma unroll
    for (int rr = 0; rr < 8; ++rr) acc[rr] = bv;

    #pragma unroll 2
    for (int k = 0; k < K; ++k) {
        const float wv = Wl[k * 64 + lane];
        #pragma unroll
        for (int rr = 0; rr < 8; ++rr)
            acc[rr] = fmaf(rowsS[(wave * 8 + rr) * K + k], wv, acc[rr]);
    }

    #pragma unroll
    for (int rr = 0; rr < 8; ++rr) {
        const int row = row0 + wave * 8 + rr;
        if (row < R) {
            const float v = fmaxf(acc[rr], 0.f);
            if (MODE == 0) out32[(size_t)row * 64 + lane] = v;
            out16[(size_t)row * 64 + lane] = (_Float16)v;
        }
    }
}

// ---------------------------------------------------------------------------
// One-time edge-net weight prep v2 (round-13 validated): coalesced per-wave
// fragment layout. 16B slot (kc, wn, tn, ks, lane) at uint4 index
// kc*512 + ((wn*2+tn)*2+ks)*64 + lane. Content: M[kc*64+(kg+ks*4)*8+m][o],
// o = wn*32+tn*16+l15; M = eW2 rows then eb2 bias chunk (t==1).
// ---------------------------------------------------------------------------
__global__ __launch_bounds__(256)
void prep_w_kernel(const float* __restrict__ eW2, const float* __restrict__ eb2,
                   unsigned short* __restrict__ w_staged)
{
    int slot = blockIdx.x * 256 + threadIdx.x;     // 65*512 slots
    if (slot >= 65 * 512) return;
    int kc   = slot >> 9;
    int s    = slot & 511;
    int sub  = s >> 6, lane = s & 63;
    int wn   = sub >> 2, tn = (sub >> 1) & 1, ks = sub & 1;
    int kg   = lane >> 4, l15 = lane & 15;
    int o    = wn * 32 + tn * 16 + l15;
    int seg  = kg + ks * 4;
    int j0   = kc * 64 + seg * 8;
    unsigned int packed[4];
    #pragma unroll
    for (int p = 0; p < 4; ++p) {
        int j = j0 + p * 2;
        float v0 = (j     < 4096) ? eW2[(size_t)j * 64 + o]       : eb2[(size_t)(j - 4096) * 64 + o];
        float v1 = (j + 1 < 4096) ? eW2[(size_t)(j + 1) * 64 + o] : eb2[(size_t)(j + 1 - 4096) * 64 + o];
        packed[p] = (unsigned int)f2h(v0) | ((unsigned int)f2h(v1) << 16);
    }
    uint4 st = {packed[0], packed[1], packed[2], packed[3]};
    ((uint4*)w_staged)[slot] = st;
}

// ---------------------------------------------------------------------------
// One-time GRU weight prep: WiT/WhT[n][k] = (f16) W[k*192+n].
// ---------------------------------------------------------------------------
__global__ __launch_bounds__(256)
void prep_gruw_kernel(const float* __restrict__ Wi, const float* __restrict__ Wh,
                      _Float16* __restrict__ WiT, _Float16* __restrict__ WhT)
{
    int idx = blockIdx.x * 256 + threadIdx.x;
    if (idx >= 2 * 12288) return;
    const float* W = (idx < 12288) ? Wi : Wh;
    _Float16*    O = (idx < 12288) ? WiT : WhT;
    int r = idx & 12287;
    int n = r >> 6, k = r & 63;
    O[n * 64 + k] = (_Float16)W[(size_t)k * 192 + n];
}

// ---------------------------------------------------------------------------
// One-time Set2Set LSTM weight prep: k-block row-major f16 (coalesced).
// ---------------------------------------------------------------------------
__global__ __launch_bounds__(256)
void prep_s2sw_kernel(const float* __restrict__ lWi0, const float* __restrict__ lWh0,
                      const float* __restrict__ lWi1, const float* __restrict__ lWh1,
                      const float* __restrict__ lWi2, const float* __restrict__ lWh2,
                      _Float16* __restrict__ WB0, _Float16* __restrict__ WB1,
                      _Float16* __restrict__ WB2)
{
    int idx = blockIdx.x * 256 + threadIdx.x;   // 114688 total
    if (idx < 49152) {
        int k = idx >> 8, n = idx & 255;
        float v = (k < 128) ? lWi0[(size_t)k * 256 + n] : lWh0[(size_t)(k - 128) * 256 + n];
        WB0[((k >> 3) * 2048) + n * 8 + (k & 7)] = (_Float16)v;
    } else if (idx < 81920) {
        int r = idx - 49152;
        int k = r >> 8, n = r & 255;
        float v = (k < 64) ? lWi1[(size_t)k * 256 + n] : lWh1[(size_t)(k - 64) * 256 + n];
        WB1[((k >> 3) * 2048) + n * 8 + (k & 7)] = (_Float16)v;
    } else if (idx < 114688) {
        int r = idx - 81920;
        int k = r >> 8, n = r & 255;
        float v = (k < 64) ? lWi2[(size_t)k * 256 + n] : lWh2[(size_t)(k - 64) * 256 + n];
        WB2[((k >> 3) * 2048) + n * 8 + (k & 7)] = (_Float16)v;
    }
}

// ---------------------------------------------------------------------------
// MFMA NNConv message v4: 128 edges/block, 512 threads / 8 waves.
// Round-13 analysis: each 64-edge block streamed the ENTIRE 532KB B matrix
// from L2 (782 blocks -> 416MB/dispatch); L2 BW was the largest per-chunk
// term. 128-edge blocks halve block count -> halve B traffic; the 4 same-wn
// waves read identical fragment lines (L1 serves 3 of 4). Per-wave code is
// byte-identical to the round-13-validated rotation (8 MFMA / 4 loads /
// depth-4 slots); only wm's range (0..3) and the tS tile (64x134) change.
// ---------------------------------------------------------------------------
__global__ __launch_bounds__(512, 4)
void msg_mfma_kernel(const _Float16* __restrict__ t16, const _Float16* __restrict__ h16,
                     const int* __restrict__ src, const int* __restrict__ dst,
                     const unsigned short* __restrict__ w_staged,
                     float* __restrict__ msum, int E)
{
    __shared__ _Float16 tS[64 * 134];    // [k][e+pad], 128 edges

    const int tid  = threadIdx.x;
    const int lane = tid & 63;
    const int wave = tid >> 6;           // 0..7
    const int wn   = wave & 1;
    const int wm   = wave >> 1;          // 0..3
    const int e0   = blockIdx.x * 128;

    // stage t tile transposed into tS[k][e] (f16)
    #pragma unroll
    for (int p = 0; p < 2; ++p) {
        int slot = tid + p * 512;               // 0..1023
        int e = slot >> 3, k0 = (slot & 7) * 8;
        int ee = e0 + e;
        half8v tv8 = (half8v)(_Float16)0.f;
        if (ee < E) tv8 = ((const half8v*)(t16 + (size_t)ee * 64))[slot & 7];
        #pragma unroll
        for (int j = 0; j < 8; ++j)
            tS[(k0 + j) * 134 + e] = tv8[j];
    }

    const int l15 = lane & 15;
    const int kg  = lane >> 4;          // 0..3

    // resident h16 A-fragments (gru-validated 16x16x32 A layout)
    half8v Hh[2][2];
    #pragma unroll
    for (int tm = 0; tm < 2; ++tm) {
        const int edge = e0 + wm * 32 + tm * 16 + l15;
        const int sidx = (edge < E) ? src[edge] : 0;
        const half8v* hp = (const half8v*)(h16 + (size_t)sidx * 64);
        Hh[tm][0] = hp[kg];
        Hh[tm][1] = hp[kg + 4];
    }

    const uint4* W4  = (const uint4*)w_staged;
    const int    wb  = wn * 256 + lane;   // fragment base within chunk

    // 4 rotation slots x 4 fragments (tn0ks0, tn0ks1, tn1ks0, tn1ks1)
    uint4 S0a, S0b, S0c, S0d, S1a, S1b, S1c, S1d;
    uint4 S2a, S2b, S2c, S2d, S3a, S3b, S3c, S3d;

#define LOADC(A, B, C, D, cc)                                         \
    { size_t off = (size_t)(cc) * 512 + wb;                           \
      A = W4[off]; B = W4[off + 64]; C = W4[off + 128]; D = W4[off + 192]; }

#define COMP(A, B, C, D, TV0, TV1)                                            \
    { half8v af00 = Hh[0][0] * (TV0), af01 = Hh[0][1] * (TV0);                \
      half8v af10 = Hh[1][0] * (TV1), af11 = Hh[1][1] * (TV1);                \
      half8v b00 = u2h(A), b01 = u2h(B), b10 = u2h(C), b11 = u2h(D);          \
      acc00 = __builtin_amdgcn_mfma_f32_16x16x32_f16(af00, b00, acc00, 0,0,0);\
      acc01 = __builtin_amdgcn_mfma_f32_16x16x32_f16(af00, b10, acc01, 0,0,0);\
      acc10 = __builtin_amdgcn_mfma_f32_16x16x32_f16(af10, b00, acc10, 0,0,0);\
      acc11 = __builtin_amdgcn_mfma_f32_16x16x32_f16(af10, b10, acc11, 0,0,0);\
      acc00 = __builtin_amdgcn_mfma_f32_16x16x32_f16(af01, b01, acc00, 0,0,0);\
      acc01 = __builtin_amdgcn_mfma_f32_16x16x32_f16(af01, b11, acc01, 0,0,0);\
      acc10 = __builtin_amdgcn_mfma_f32_16x16x32_f16(af11, b01, acc10, 0,0,0);\
      acc11 = __builtin_amdgcn_mfma_f32_16x16x32_f16(af11, b11, acc11, 0,0,0); }

    LOADC(S0a, S0b, S0c, S0d, 0)
    LOADC(S1a, S1b, S1c, S1d, 1)
    LOADC(S2a, S2b, S2c, S2d, 2)
    LOADC(S3a, S3b, S3c, S3d, 3)

    f32x4 acc00, acc01, acc10, acc11;
    #pragma unroll
    for (int j = 0; j < 4; ++j) { acc00[j] = 0.f; acc01[j] = 0.f; acc10[j] = 0.f; acc11[j] = 0.f; }

    __syncthreads();   // tS visible (one-time)

    const int tvb0 = wm * 32 + l15, tvb1 = wm * 32 + 16 + l15;

    for (int c = 0; c < 64; c += 4) {
        _Float16 ta0 = tS[(c + 0) * 134 + tvb0], tb0 = tS[(c + 0) * 134 + tvb1];
        _Float16 ta1 = tS[(c + 1) * 134 + tvb0], tb1 = tS[(c + 1) * 134 + tvb1];
        _Float16 ta2 = tS[(c + 2) * 134 + tvb0], tb2 = tS[(c + 2) * 134 + tvb1];
        _Float16 ta3 = tS[(c + 3) * 134 + tvb0], tb3 = tS[(c + 3) * 134 + tvb1];

        COMP(S0a, S0b, S0c, S0d, ta0, tb0)
        if (c + 4 <= 64) LOADC(S0a, S0b, S0c, S0d, c + 4)
        COMP(S1a, S1b, S1c, S1d, ta1, tb1)
        if (c + 5 <= 64) LOADC(S1a, S1b, S1c, S1d, c + 5)
        COMP(S2a, S2b, S2c, S2d, ta2, tb2)
        if (c + 6 <= 64) LOADC(S2a, S2b, S2c, S2d, c + 6)
        COMP(S3a, S3b, S3c, S3d, ta3, tb3)
        if (c + 7 <= 64) LOADC(S3a, S3b, S3c, S3d, c + 7)
    }
    // bias chunk 64 (t == 1), resident in slot 0 (loaded at c=60)
    {
        const _Float16 one = (_Float16)1.0f;
        COMP(S0a, S0b, S0c, S0d, one, one)
    }
#undef LOADC
#undef COMP

    // epilogue: 16x16 C layout (gru-validated): col=l15, row=kg*4+j
    f32x4 acc[2][2] = {{acc00, acc01}, {acc10, acc11}};
    #pragma unroll
    for (int tm = 0; tm < 2; ++tm) {
        #pragma unroll
        for (int j = 0; j < 4; ++j) {
            const int edge = e0 + wm * 32 + tm * 16 + kg * 4 + j;
            if (edge >= E) continue;
            const int d = dst[edge];
            #pragma unroll
            for (int tn = 0; tn < 2; ++tn)
                atomicAdd(&msum[(size_t)d * 64 + wn * 32 + tn * 16 + l15], acc[tm][tn][j]);
        }
    }
}

// ---------------------------------------------------------------------------
// MFMA GRU — round-4 known-good version (weights LDS-staged per block).
// ---------------------------------------------------------------------------
__global__ __launch_bounds__(256, 2)
void gru_mfma_kernel(const float* __restrict__ msum, float* __restrict__ h,
                     _Float16* __restrict__ h16,
                     const _Float16* __restrict__ WiT, const _Float16* __restrict__ WhT,
                     const float* __restrict__ bi, const float* __restrict__ bh,
                     const float* __restrict__ conv_b, int N)
{
    __shared__ _Float16 BtI[192 * 72];   // [n][k+pad]
    __shared__ _Float16 BtH[192 * 72];
    __shared__ _Float16 Am[64 * 72];     // [row][k+pad]
    __shared__ _Float16 Ah[64 * 72];

    const int tid  = threadIdx.x;
    const int lane = tid & 63;
    const int wave = tid >> 6;
    const int m0   = wave * 16;
    const int row0 = blockIdx.x * 64;

    #pragma unroll
    for (int p = 0; p < 6; ++p) {
        int slot = tid + p * 256;            // 0..1535
        int n = slot >> 3, k0 = (slot & 7) * 8;
        uint4 vi = ((const uint4*)WiT)[slot];
        uint4 vh = ((const uint4*)WhT)[slot];
        *(uint4*)&BtI[n * 72 + k0] = vi;
        *(uint4*)&BtH[n * 72 + k0] = vh;
    }
    #pragma unroll
    for (int p = 0; p < 4; ++p) {
        int idx = tid + p * 256;             // 0..1023
        int r = idx >> 4, k4 = (idx & 15) * 4;
        int row = row0 + r;
        float4 mv = make_float4(0.f, 0.f, 0.f, 0.f);
        if (row < N) mv = *(const float4*)&msum[(size_t)row * 64 + k4];
        float4 cb = *(const float4*)&conv_b[k4];
        union { _Float16 hx[4]; uint2 u2; } pk;
        pk.hx[0] = (_Float16)fmaxf(mv.x + cb.x, 0.f);
        pk.hx[1] = (_Float16)fmaxf(mv.y + cb.y, 0.f);
        pk.hx[2] = (_Float16)fmaxf(mv.z + cb.z, 0.f);
        pk.hx[3] = (_Float16)fmaxf(mv.w + cb.w, 0.f);
        *(uint2*)&Am[r * 72 + k4] = pk.u2;
    }
    #pragma unroll
    for (int p = 0; p < 2; ++p) {
        int idx = tid + p * 256;             // 0..511
        int r = idx >> 3, k0 = (idx & 7) * 8;
        int row = row0 + r;
        uint4 v = {0u, 0u, 0u, 0u};
        if (row < N) v = *(const uint4*)&h16[(size_t)row * 64 + k0];
        *(uint4*)&Ah[r * 72 + k0] = v;
    }
    __syncthreads();

    const int l15 = lane & 15;

    f32x4 acc_i[12], acc_h[12];
    #pragma unroll
    for (int nt = 0; nt < 12; ++nt) {
        #pragma unroll
        for (int j = 0; j < 4; ++j) { acc_i[nt][j] = 0.f; acc_h[nt][j] = 0.f; }
    }

    #pragma unroll
    for (int ks = 0; ks < 2; ++ks) {
        const int ka = ks * 32 + (lane >> 4) * 8;
        half8v am = *(const half8v*)&Am[(m0 + l15) * 72 + ka];
        half8v ah = *(const half8v*)&Ah[(m0 + l15) * 72 + ka];
        #pragma unroll
        for (int nt = 0; nt < 12; ++nt) {
            half8v b_i = *(const half8v*)&BtI[(nt * 16 + l15) * 72 + ka];
            half8v b_h = *(const half8v*)&BtH[(nt * 16 + l15) * 72 + ka];
            acc_i[nt] = __builtin_amdgcn_mfma_f32_16x16x32_f16(am, b_i, acc_i[nt], 0, 0, 0);
            acc_h[nt] = __builtin_amdgcn_mfma_f32_16x16x32_f16(ah, b_h, acc_h[nt], 0, 0, 0);
        }
    }

    const int rgrp = lane >> 4;
    #pragma unroll
    for (int nt0 = 0; nt0 < 4; ++nt0) {
        const int c = nt0 * 16 + l15;
        const float bir = bi[c],        bhr = bh[c];
        const float biz = bi[64 + c],   bhz = bh[64 + c];
        const float bin = bi[128 + c],  bhn = bh[128 + c];
        #pragma unroll
        for (int j = 0; j < 4; ++j) {
            const int row = row0 + m0 + rgrp * 4 + j;
            if (row >= N) continue;
            float rg = sigf(acc_i[nt0][j]      + bir + acc_h[nt0][j]      + bhr);
            float zg = sigf(acc_i[4 + nt0][j]  + biz + acc_h[4 + nt0][j]  + bhz);
            float ng = tanhf(acc_i[8 + nt0][j] + bin + rg * (acc_h[8 + nt0][j] + bhn));
            float hold = h[(size_t)row * 64 + c];
            float hv = (1.f - zg) * ng + zg * hold;
            h[(size_t)row * 64 + c]   = hv;
            h16[(size_t)row * 64 + c] = (_Float16)hv;
        }
    }
}

// ---------------------------------------------------------------------------
// Per-thread gate dot: k-block row-major f16 weights (coalesced half8v).
// ---------------------------------------------------------------------------
__device__ __forceinline__ float gate_dot8(const _Float16* __restrict__ WB,
                                           int tid, const float* __restrict__ xs,
                                           int nblk)
{
    float a0 = 0.f, a1 = 0.f, a2 = 0.f, a3 = 0.f;
    #pragma unroll 4
    for (int b = 0; b < nblk; ++b) {
        half8v w = *(const half8v*)(WB + (size_t)b * 2048 + tid * 8);
        float4 xa = *(const float4*)&xs[b * 8];
        float4 xb = *(const float4*)&xs[b * 8 + 4];
        a0 = fmaf((float)w[0], xa.x, a0);
        a1 = fmaf((float)w[1], xa.y, a1);
        a2 = fmaf((float)w[2], xa.z, a2);
        a3 = fmaf((float)w[3], xa.w, a3);
        a0 = fmaf((float)w[4], xb.x, a0);
        a1 = fmaf((float)w[5], xb.y, a1);
        a2 = fmaf((float)w[6], xb.z, a2);
        a3 = fmaf((float)w[7], xb.w, a3);
    }
    return (a0 + a1) + (a2 + a3);
}

// ---------------------------------------------------------------------------
// Fused Set2Set + head: 1 graph per block, f16 k-block weights, f32 state.
// ---------------------------------------------------------------------------
__global__ __launch_bounds__(256)
void set2set_kernel(const float* __restrict__ h,
                    const _Float16* __restrict__ WB0, const _Float16* __restrict__ WB1,
                    const _Float16* __restrict__ WB2,
                    const float* __restrict__ lb0, const float* __restrict__ lb1,
                    const float* __restrict__ lb2,
                    const float* __restrict__ pW, const float* __restrict__ pb,
                    const float* __restrict__ fW, const float* __restrict__ fb,
                    float* __restrict__ out)
{
    const int g   = blockIdx.x;
    const int tid = threadIdx.x;

    __shared__ float hl[25 * 65];
    __shared__ float hs[3][64], cs[3][64];
    __shared__ float qstar[128];
    __shared__ __align__(16) float xs[192];
    __shared__ float gates[256];
    __shared__ float als[32];

    for (int idx = tid; idx < 25 * 64; idx += 256) {
        int n = idx >> 6, d = idx & 63;
        hl[n * 65 + d] = h[((size_t)g * 25 + n) * 64 + d];
    }
    if (tid < 128) qstar[tid] = 0.f;
    if (tid < 64) {
        #pragma unroll
        for (int l = 0; l < 3; ++l) { hs[l][tid] = 0.f; cs[l][tid] = 0.f; }
    }
    __syncthreads();

    for (int it = 0; it < 3; ++it) {
        // ---- layer 0 (K = 128 + 64) ----
        if (tid < 128) xs[tid] = qstar[tid];
        else if (tid < 192) xs[tid] = hs[0][tid - 128];
        __syncthreads();
        gates[tid] = lb0[tid] + gate_dot8(WB0, tid, xs, 24);
        __syncthreads();
        if (tid < 64) {
            float ig = sigf(gates[tid]);
            float fg = sigf(gates[64 + tid]);
            float gg = tanhf(gates[128 + tid]);
            float og = sigf(gates[192 + tid]);
            float cv = fg * cs[0][tid] + ig * gg;
            cs[0][tid] = cv;
            hs[0][tid] = og * tanhf(cv);
        }
        __syncthreads();
        // ---- layer 1 (K = 64 + 64) ----
        if (tid < 64) xs[tid] = hs[0][tid];
        else if (tid < 128) xs[tid] = hs[1][tid - 64];
        __syncthreads();
        gates[tid] = lb1[tid] + gate_dot8(WB1, tid, xs, 16);
        __syncthreads();
        if (tid < 64) {
            float ig = sigf(gates[tid]);
            float fg = sigf(gates[64 + tid]);
            float gg = tanhf(gates[128 + tid]);
            float og = sigf(gates[192 + tid]);
            float cv = fg * cs[1][tid] + ig * gg;
            cs[1][tid] = cv;
            hs[1][tid] = og * tanhf(cv);
        }
        __syncthreads();
        // ---- layer 2 (K = 64 + 64) ----
        if (tid < 64) xs[tid] = hs[1][tid];
        else if (tid < 128) xs[tid] = hs[2][tid - 64];
        __syncthreads();
        gates[tid] = lb2[tid] + gate_dot8(WB2, tid, xs, 16);
        __syncthreads();
        if (tid < 64) {
            float ig = sigf(gates[tid]);
            float fg = sigf(gates[64 + tid]);
            float gg = tanhf(gates[128 + tid]);
            float og = sigf(gates[192 + tid]);
            float cv = fg * cs[2][tid] + ig * gg;
            cs[2][tid] = cv;
            hs[2][tid] = og * tanhf(cv);
        }
        __syncthreads();
        // ---- attention over this graph's 25 nodes; q = hs[2] ----
        float ev = -1e30f;
        if (tid < 25) {
            float acc = 0.f;
            for (int d = 0; d < 64; ++d)
                acc = fmaf(hl[tid * 65 + d], hs[2][d], acc);
            ev = acc;
        }
        if (tid < 64) {
            float mx = ev;
            #pragma unroll
            for (int off = 16; off; off >>= 1) mx = fmaxf(mx, __shfl_xor(mx, off, 32));
            float ex = (tid < 25) ? expf(ev - mx) : 0.f;
            float sm = ex;
            #pragma unroll
            for (int off = 16; off; off >>= 1) sm += __shfl_xor(sm, off, 32);
            if (tid < 25) als[tid] = ex / sm;
        }
        __syncthreads();
        if (tid < 64) {
            float rdt = 0.f;
            #pragma unroll
            for (int n = 0; n < 25; ++n) rdt = fmaf(als[n], hl[n * 65 + tid], rdt);
            qstar[tid]      = hs[2][tid];
            qstar[64 + tid] = rdt;
        }
        __syncthreads();
    }

    if (tid < 64) {
        float acc = pb[tid];
        #pragma unroll 8
        for (int k = 0; k < 128; ++k)
            acc = fmaf(qstar[k], pW[(size_t)k * 64 + tid], acc);
        float part = fmaxf(acc, 0.f) * fW[tid];
        #pragma unroll
        for (int off = 32; off; off >>= 1) part += __shfl_xor(part, off, 64);
        if (tid == 0) out[g] = 1.f / (1.f + expf(-(part + fb[0])));
    }
}

// ---------------------------------------------------------------------------
extern "C" void kernel_launch(void* const* d_in, const int* in_sizes, int n_in,
                              void* d_out, int out_size, void* d_ws, size_t ws_size,
                              hipStream_t stream)
{
    const float* n_feats = (const float*)d_in[0];
    const float* e_feats = (const float*)d_in[1];
    const int*   src     = (const int*)d_in[2];
    const int*   dst     = (const int*)d_in[3];
    const float* proj_W  = (const float*)d_in[5];
    const float* proj_b  = (const float*)d_in[6];
    const float* eW1     = (const float*)d_in[7];
    const float* eb1     = (const float*)d_in[8];
    const float* eW2     = (const float*)d_in[9];
    const float* eb2     = (const float*)d_in[10];
    const float* conv_b  = (const float*)d_in[11];
    const float* gWi     = (const float*)d_in[12];
    const float* gWh     = (const float*)d_in[13];
    const float* gbi     = (const float*)d_in[14];
    const float* gbh     = (const float*)d_in[15];
    const float* lWi0    = (const float*)d_in[16];
    const float* lWh0    = (const float*)d_in[17];
    const float* lb0     = (const float*)d_in[18];
    const float* lWi1    = (const float*)d_in[19];
    const float* lWh1    = (const float*)d_in[20];
    const float* lb1     = (const float*)d_in[21];
    const float* lWi2    = (const float*)d_in[22];
    const float* lWh2    = (const float*)d_in[23];
    const float* lb2     = (const float*)d_in[24];
    const float* pW      = (const float*)d_in[25];
    const float* pb      = (const float*)d_in[26];
    const float* fW      = (const float*)d_in[27];
    const float* fb      = (const float*)d_in[28];

    const int N = in_sizes[0] / 74;   // 25000
    const int E = in_sizes[1] / 12;   // 50000
    const int G = out_size;           // 1000

    float* ws   = (float*)d_ws;
    float* h    = ws;                                        // N*64 f32
    float* msum = h + (size_t)N * 64;                        // N*64 f32
    _Float16* h16 = (_Float16*)(msum + (size_t)N * 64);     // N*64 f16
    _Float16* t16 = h16 + (size_t)N * 64;                   // E*64 f16
    unsigned short* w_staged = (unsigned short*)(t16 + (size_t)E * 64); // 65*4096 shorts
    _Float16* WiT = (_Float16*)(w_staged + 65 * 4096);      // 192*64 f16
    _Float16* WhT = WiT + 12288;                            // 192*64 f16
    _Float16* WB0 = WhT + 12288;                            // 192*256 f16
    _Float16* WB1 = WB0 + 49152;                            // 128*256 f16
    _Float16* WB2 = WB1 + 32768;                            // 128*256 f16

    // one-time weight prep
    prep_w_kernel<<<130, 256, 0, stream>>>(eW2, eb2, w_staged);
    prep_gruw_kernel<<<96, 256, 0, stream>>>(gWi, gWh, WiT, WhT);
    prep_s2sw_kernel<<<448, 256, 0, stream>>>(lWi0, lWh0, lWi1, lWh1, lWi2, lWh2,
                                              WB0, WB1, WB2);

    // node projection (h f32 + f16) and edge-net first layer (f16)
    rowmat_relu_t<74, 0><<<(N + 31) / 32, 256, 0, stream>>>(n_feats, proj_W, proj_b, h, h16, N);
    rowmat_relu_t<12, 1><<<(E + 31) / 32, 256, 0, stream>>>(e_feats, eW1, eb1, nullptr, t16, E);

    // 3 rounds of message passing + GRU
    for (int it = 0; it < 3; ++it) {
        hipMemsetAsync(msum, 0, (size_t)N * 64 * sizeof(float), stream);
        msg_mfma_kernel<<<(E + 127) / 128, 512, 0, stream>>>(t16, h16, src, dst, w_staged, msum, E);
        gru_mfma_kernel<<<(N + 63) / 64, 256, 0, stream>>>(msum, h, h16, WiT, WhT,
                                                           gbi, gbh, conv_b, N);
    }

    // fused Set2Set (3 iters) + predict head: 1 graph per block
    set2set_kernel<<<G, 256, 0, stream>>>(h, WB0, WB1, WB2, lb0, lb1, lb2,
                                          pW, pb, fW, fb, (float*)d_out);
}